// Round 9
// baseline (216.551 us; speedup 1.0000x reference)
//
#include <hip/hip_runtime.h>
#include <hip/hip_bf16.h>

#define DIM   384
#define NH    12
#define HD    32
#define HWSZ  1024
#define BATCH 8
#define SCALE 0.17677669529663687f          // 32^-0.5
#define EXP_K (SCALE * 1.4426950408889634f) // SCALE * log2(e): q pre-scale for exp2

typedef __attribute__((ext_vector_type(8))) short bf16x8;
typedef __attribute__((ext_vector_type(4))) float floatx4;

__device__ __forceinline__ unsigned short f2bf(float x) {
    union { __hip_bfloat16 h; unsigned short u; } c;
    c.h = __float2bfloat16(x);          // native v_cvt (RNE)
    return c.u;
}
__device__ __forceinline__ float bf2f(unsigned short h) {
    union { unsigned int u; float f; } v; v.u = ((unsigned int)h) << 16;
    return v.f;
}

// ---------------------------------------------------------------------------
// Weight pre-cast: qkvo_w (1536x384) and proj_w (384x384) f32 -> bf16, once.
// ---------------------------------------------------------------------------
__global__ __launch_bounds__(256) void cast_w(
    const float* __restrict__ wa, const float* __restrict__ wb,
    unsigned short* __restrict__ da, unsigned short* __restrict__ db, int na8)
{
    const int idx = blockIdx.x * 256 + threadIdx.x;
    const float* src; unsigned short* dst; int i;
    if (idx < na8) { src = wa; dst = da; i = idx; }
    else           { src = wb; dst = db; i = idx - na8; }
    float4 f0 = *(const float4*)&src[i * 8];
    float4 f1 = *(const float4*)&src[i * 8 + 4];
    ushort4 h0 = make_ushort4(f2bf(f0.x), f2bf(f0.y), f2bf(f0.z), f2bf(f0.w));
    ushort4 h1 = make_ushort4(f2bf(f1.x), f2bf(f1.y), f2bf(f1.z), f2bf(f1.w));
    *(ushort4*)&dst[i * 8] = h0;
    *(ushort4*)&dst[i * 8 + 4] = h1;
}

// ---------------------------------------------------------------------------
// Transpose+cast: in [B][C][N] f32 -> out [B][N][C] bf16.  grid(N/32, C/32, B)
// ---------------------------------------------------------------------------
__global__ __launch_bounds__(256) void tcast_f32(
    const float* __restrict__ in, unsigned short* __restrict__ out, int C, int N)
{
    __shared__ __align__(16) unsigned short t[32][36];
    const int n0 = blockIdx.x * 32, c0 = blockIdx.y * 32, b = blockIdx.z;
    const float* ib = in + (size_t)b * C * N;
    unsigned short* ob = out + (size_t)b * N * C;
    const int tid = threadIdx.x;
    const int r = tid >> 3, q = (tid & 7) * 4;
    float4 f = *(const float4*)&ib[(size_t)(c0 + r) * N + n0 + q];
    ushort4 h = make_ushort4(f2bf(f.x), f2bf(f.y), f2bf(f.z), f2bf(f.w));
    *(ushort4*)&t[r][q] = h;
    __syncthreads();
    ushort4 o;
    o.x = t[q + 0][r]; o.y = t[q + 1][r]; o.z = t[q + 2][r]; o.w = t[q + 3][r];
    *(ushort4*)&ob[(size_t)(n0 + r) * C + c0 + q] = o;
}

// Same, bf16 input.
__global__ __launch_bounds__(256) void tcast_b16(
    const unsigned short* __restrict__ in, unsigned short* __restrict__ out, int C, int N)
{
    __shared__ __align__(16) unsigned short t[32][36];
    const int n0 = blockIdx.x * 32, c0 = blockIdx.y * 32, b = blockIdx.z;
    const unsigned short* ib = in + (size_t)b * C * N;
    unsigned short* ob = out + (size_t)b * N * C;
    const int tid = threadIdx.x;
    const int r = tid >> 3, q = (tid & 7) * 4;
    ushort4 h = *(const ushort4*)&ib[(size_t)(c0 + r) * N + n0 + q];
    *(ushort4*)&t[r][q] = h;
    __syncthreads();
    ushort4 o;
    o.x = t[q + 0][r]; o.y = t[q + 1][r]; o.z = t[q + 2][r]; o.w = t[q + 3][r];
    *(ushort4*)&ob[(size_t)(n0 + r) * C + c0 + q] = o;
}

// ---------------------------------------------------------------------------
// MFMA GEMM, 128x128 tile, BK=32, 256 threads = 4 waves (2x2 wave grid).
// Wave owns a 64x64 quadrant = 4x4 16x16 frags -> 16 MFMA per k-step.
// Y[b][m][n] = sum_k Wb16[m][k]*Xt[b][n][k] + bias[m]
// MODE 0 (qkvo): m<768 -> qkT[b][n][m] (q rows m<384 pre-scaled by EXP_K);
//                m>=768 -> vo[b][m-768][n].
// MODE 1 (proj): Yf[b][m][n] f32.
// ---------------------------------------------------------------------------
template<int MODE>
__global__ __launch_bounds__(256) void gemm_mfma(
    const unsigned short* __restrict__ Wb16, const unsigned short* __restrict__ Xt,
    const float* __restrict__ bias, unsigned short* __restrict__ qkT,
    unsigned short* __restrict__ vo, float* __restrict__ Yf,
    int M, int K, int N)
{
    __shared__ __align__(16) unsigned short As[128][40];  // [m][k], 80B rows
    __shared__ __align__(16) unsigned short Bs[128][40];  // [n][k]

    const int b = blockIdx.z, m0 = blockIdx.y * 128, n0 = blockIdx.x * 128;
    const int tid = threadIdx.x;
    const int w = tid >> 6, lane = tid & 63;
    const int wr = w >> 1, wc = w & 1;
    const int g = lane >> 4, c = lane & 15;

    const unsigned short* Xb = Xt + (size_t)b * N * K;

    floatx4 acc[4][4];
    #pragma unroll
    for (int i = 0; i < 4; ++i)
        #pragma unroll
        for (int j = 0; j < 4; ++j) acc[i][j] = (floatx4){0.f, 0.f, 0.f, 0.f};

    const int srow = tid >> 1, shh = (tid & 1) * 16;   // staging coords

    for (int k0 = 0; k0 < K; k0 += 32) {
        __syncthreads();
        {
            const unsigned short* wp = &Wb16[(size_t)(m0 + srow) * K + k0 + shh];
            *(bf16x8*)&As[srow][shh]     = *(const bf16x8*)wp;
            *(bf16x8*)&As[srow][shh + 8] = *(const bf16x8*)(wp + 8);
            const unsigned short* xp = &Xb[(size_t)(n0 + srow) * K + k0 + shh];
            *(bf16x8*)&Bs[srow][shh]     = *(const bf16x8*)xp;
            *(bf16x8*)&Bs[srow][shh + 8] = *(const bf16x8*)(xp + 8);
        }
        __syncthreads();

        bf16x8 af[4], bfj[4];
        #pragma unroll
        for (int i = 0; i < 4; ++i)
            af[i] = *(const bf16x8*)&As[64 * wr + 16 * i + c][8 * g];
        #pragma unroll
        for (int j = 0; j < 4; ++j)
            bfj[j] = *(const bf16x8*)&Bs[64 * wc + 16 * j + c][8 * g];
        #pragma unroll
        for (int i = 0; i < 4; ++i)
            #pragma unroll
            for (int j = 0; j < 4; ++j)
                acc[i][j] = __builtin_amdgcn_mfma_f32_16x16x32_bf16(
                    af[i], bfj[j], acc[i][j], 0, 0, 0);
    }

    // Epilogue. Lane holds D[m=m0+64wr+16i+4g+r][n=n0+64wc+16j+c].
    #pragma unroll
    for (int i = 0; i < 4; ++i) {
        const int m = m0 + 64 * wr + 16 * i + 4 * g;
        float bi[4];
        #pragma unroll
        for (int r = 0; r < 4; ++r) bi[r] = bias[m + r];

        if (MODE == 0) {
            if (m0 < 768) {
                const float qs = (m0 < 384) ? EXP_K : 1.0f;
                #pragma unroll
                for (int j = 0; j < 4; ++j) {
                    const int n = n0 + 64 * wc + 16 * j + c;
                    ushort4 h;
                    h.x = f2bf((acc[i][j][0] + bi[0]) * qs);
                    h.y = f2bf((acc[i][j][1] + bi[1]) * qs);
                    h.z = f2bf((acc[i][j][2] + bi[2]) * qs);
                    h.w = f2bf((acc[i][j][3] + bi[3]) * qs);
                    *(ushort4*)&qkT[((size_t)b * HWSZ + n) * 768 + m] = h;
                }
            } else {
                #pragma unroll
                for (int j = 0; j < 4; ++j) {
                    const int n = n0 + 64 * wc + 16 * j + c;
                    #pragma unroll
                    for (int r = 0; r < 4; ++r)
                        vo[((size_t)b * 768 + (m - 768 + r)) * HWSZ + n] =
                            f2bf(acc[i][j][r] + bi[r]);
                }
            }
        } else {
            #pragma unroll
            for (int j = 0; j < 4; ++j) {
                const int n = n0 + 64 * wc + 16 * j + c;
                #pragma unroll
                for (int r = 0; r < 4; ++r)
                    Yf[((size_t)b * M + m + r) * (size_t)N + n] = acc[i][j][r] + bi[r];
            }
        }
    }
}

// ---------------------------------------------------------------------------
// Barrier-free MFMA attention. 512 thr = 8 waves, each wave owns 16 p-rows.
// K-frags and V-frags are loaded DIRECTLY from global (qkT / vo are already in
// fragment layout); the 8KB j-tile is L1-resident and shared by all waves.
// Ps and lbuf are same-wave-only => NO __syncthreads anywhere.
// Block roles XCD-swizzled so the 8 p-blocks sharing one (b,h) K/V land on the
// same XCD's L2 (bijective remap; perf-only assumption).
// ---------------------------------------------------------------------------
__global__ __launch_bounds__(512) void attn_mfma(
    const unsigned short* __restrict__ qkT, const unsigned short* __restrict__ vo,
    unsigned short* __restrict__ res)
{
    __shared__ __align__(16) unsigned short Ps[128][72];  // [p][j], per-wave rows
    __shared__ float lbuf[128];

    // XCD-aware role swizzle: dispatch linear = x + 8*(y + 12*z); XCD ~ x.
    const int gidx = blockIdx.x * 96 + blockIdx.y + 12 * blockIdx.z;
    const int bh = gidx >> 3, pblk = gidx & 7;
    const int b = bh / 12, h = bh % 12;
    const int p0 = pblk * 128;

    const int tid = threadIdx.x;
    const int w = tid >> 6, lane = tid & 63;
    const int g = lane >> 4, c = lane & 15;

    const unsigned short* qkTb = qkT + (size_t)b * HWSZ * 768;
    const unsigned short* kb   = qkTb + 384 + h * HD;         // row j: kb[j*768 + d]
    const unsigned short* vb   = vo + ((size_t)b * 768 + h * HD) * HWSZ;

    // Q B-frag (hoisted): col p = p0+16w+c, k d = 8g+i (q pre-scaled by EXP_K)
    bf16x8 qf = *(const bf16x8*)&qkTb[(size_t)(p0 + 16 * w + c) * 768 + h * HD + 8 * g];

    floatx4 oacc0 = (floatx4){0.f, 0.f, 0.f, 0.f};
    floatx4 oacc1 = (floatx4){0.f, 0.f, 0.f, 0.f};
    float Lacc = 0.f;

    for (int j0 = 0; j0 < HWSZ; j0 += 64) {
        // QK^T (swapped): St = mfma(K-frag, Q-frag); K-frag direct from global
        #pragma unroll
        for (int jb = 0; jb < 4; ++jb) {
            bf16x8 kf = *(const bf16x8*)&kb[(size_t)(j0 + jb * 16 + c) * 768 + 8 * g];
            floatx4 st = (floatx4){0.f, 0.f, 0.f, 0.f};
            st = __builtin_amdgcn_mfma_f32_16x16x32_bf16(kf, qf, st, 0, 0, 0);
            float e0 = exp2f(st[0]);
            float e1 = exp2f(st[1]);
            float e2 = exp2f(st[2]);
            float e3 = exp2f(st[3]);
            Lacc += (e0 + e1) + (e2 + e3);
            ushort4 pe = make_ushort4(f2bf(e0), f2bf(e1), f2bf(e2), f2bf(e3));
            *(ushort4*)&Ps[16 * w + c][jb * 16 + 4 * g] = pe;
        }

        // PV: A = own wave's Ps rows; B = V-frag direct from global ([d][j] layout)
        #pragma unroll
        for (int jk = 0; jk < 2; ++jk) {
            bf16x8 pf  = *(const bf16x8*)&Ps[16 * w + c][jk * 32 + 8 * g];
            bf16x8 vf0 = *(const bf16x8*)&vb[(size_t)c * HWSZ + j0 + jk * 32 + 8 * g];
            bf16x8 vf1 = *(const bf16x8*)&vb[(size_t)(16 + c) * HWSZ + j0 + jk * 32 + 8 * g];
            oacc0 = __builtin_amdgcn_mfma_f32_16x16x32_bf16(pf, vf0, oacc0, 0, 0, 0);
            oacc1 = __builtin_amdgcn_mfma_f32_16x16x32_bf16(pf, vf1, oacc1, 0, 0, 0);
        }
    }

    // Row sums l[p]: reduce partials across the 4 g-groups (same wave)
    Lacc += __shfl_xor(Lacc, 16, 64);
    Lacc += __shfl_xor(Lacc, 32, 64);
    if (g == 0) lbuf[16 * w + c] = Lacc;   // same-wave producer/consumer

    float linv[4];
    #pragma unroll
    for (int r = 0; r < 4; ++r) linv[r] = 1.0f / lbuf[16 * w + 4 * g + r];

    // O D-frag: lane holds O[p=p0+16w+4g+r][d=dblk*16+c]; 4 consecutive p -> 8B
    unsigned short* rp = res + ((size_t)b * DIM + h * HD) * HWSZ;
    const int pbase = p0 + 16 * w + 4 * g;
    ushort4 h0, h1;
    h0.x = f2bf(oacc0[0] * linv[0]); h0.y = f2bf(oacc0[1] * linv[1]);
    h0.z = f2bf(oacc0[2] * linv[2]); h0.w = f2bf(oacc0[3] * linv[3]);
    h1.x = f2bf(oacc1[0] * linv[0]); h1.y = f2bf(oacc1[1] * linv[1]);
    h1.z = f2bf(oacc1[2] * linv[2]); h1.w = f2bf(oacc1[3] * linv[3]);
    *(ushort4*)&rp[(size_t)c * HWSZ + pbase] = h0;
    *(ushort4*)&rp[(size_t)(16 + c) * HWSZ + pbase] = h1;
}

// ---------------------------------------------------------------------------
// LePE 5x5 depthwise on v + bias, fused gate: gated = (res + lepe(v)) * o.
// ---------------------------------------------------------------------------
__global__ __launch_bounds__(256) void lepe_mul(
    const unsigned short* __restrict__ vo, const float* __restrict__ lw,
    const float* __restrict__ lb, const unsigned short* __restrict__ res,
    unsigned short* __restrict__ gated)
{
    const int cch = blockIdx.x, b = blockIdx.y;
    const unsigned short* v  = vo + ((size_t)b * 768 + cch) * HWSZ;
    const unsigned short* o  = vo + ((size_t)b * 768 + 384 + cch) * HWSZ;
    const unsigned short* rp = res + ((size_t)b * DIM + cch) * HWSZ;
    unsigned short* gp = gated + ((size_t)b * DIM + cch) * HWSZ;

    __shared__ float vs[1024];
    __shared__ float wgt[25];

    const int tid = threadIdx.x;
    {
        ushort4 hv = *(const ushort4*)&v[tid * 4];
        vs[tid * 4 + 0] = bf2f(hv.x); vs[tid * 4 + 1] = bf2f(hv.y);
        vs[tid * 4 + 2] = bf2f(hv.z); vs[tid * 4 + 3] = bf2f(hv.w);
    }
    if (tid < 25) wgt[tid] = lw[cch * 25 + tid];
    __syncthreads();

    const float bias = lb[cch];
    const int q0 = tid * 4;
    const int y  = q0 >> 5;
    const int x0 = q0 & 31;

    float acc[4] = {bias, bias, bias, bias};
    #pragma unroll
    for (int ky = 0; ky < 5; ++ky) {
        int iy = y + ky - 2;
        if ((unsigned)iy < 32u) {
            #pragma unroll
            for (int kx = 0; kx < 5; ++kx) {
                float wv = wgt[ky * 5 + kx];
                #pragma unroll
                for (int u = 0; u < 4; ++u) {
                    int ix = x0 + u + kx - 2;
                    if ((unsigned)ix < 32u) acc[u] += wv * vs[iy * 32 + ix];
                }
            }
        }
    }

    ushort4 rh = *(const ushort4*)&rp[q0];
    ushort4 oh = *(const ushort4*)&o[q0];
    ushort4 outv;
    outv.x = f2bf((bf2f(rh.x) + acc[0]) * bf2f(oh.x));
    outv.y = f2bf((bf2f(rh.y) + acc[1]) * bf2f(oh.y));
    outv.z = f2bf((bf2f(rh.z) + acc[2]) * bf2f(oh.z));
    outv.w = f2bf((bf2f(rh.w) + acc[3]) * bf2f(oh.w));
    *(ushort4*)&gp[q0] = outv;
}

// ---------------------------------------------------------------------------
extern "C" void kernel_launch(void* const* d_in, const int* in_sizes, int n_in,
                              void* d_out, int out_size, void* d_ws, size_t ws_size,
                              hipStream_t stream)
{
    const float* x      = (const float*)d_in[0];
    const float* qkvo_w = (const float*)d_in[1];
    const float* qkvo_b = (const float*)d_in[2];
    const float* lepe_w = (const float*)d_in[3];
    const float* lepe_b = (const float*)d_in[4];
    const float* proj_w = (const float*)d_in[5];
    const float* proj_b = (const float*)d_in[6];

    unsigned short* xt     = (unsigned short*)d_ws;                    // 8*1024*384
    unsigned short* qkT    = xt     + (size_t)BATCH * HWSZ * DIM;      // 8*1024*768
    unsigned short* vo     = qkT    + (size_t)BATCH * HWSZ * 768;      // 8*768*1024
    unsigned short* res    = vo     + (size_t)BATCH * 768 * HWSZ;      // 8*384*1024
    unsigned short* gated  = res    + (size_t)BATCH * DIM * HWSZ;      // 8*384*1024
    unsigned short* gatedT = gated  + (size_t)BATCH * DIM * HWSZ;      // 8*1024*384
    unsigned short* wqb    = gatedT + (size_t)BATCH * HWSZ * DIM;      // 1536*384
    unsigned short* wpb    = wqb    + (size_t)1536 * DIM;              // 384*384

    // 0. Pre-cast weights to bf16 (na8 = 1536*384/8, nb8 = 384*384/8)
    cast_w<<<dim3((73728 + 18432) / 256), 256, 0, stream>>>(
        qkvo_w, proj_w, wqb, wpb, 73728);

    // 1. x [b][384][1024] f32 -> xt [b][1024][384] bf16
    tcast_f32<<<dim3(32, 12, BATCH), 256, 0, stream>>>(x, xt, DIM, HWSZ);

    // 2. QKVO projection -> qkT (q,k transposed; q pre-scaled) + vo (v,o normal)
    gemm_mfma<0><<<dim3(8, 12, BATCH), 256, 0, stream>>>(
        wqb, xt, qkvo_b, qkT, vo, nullptr, 4 * DIM, DIM, HWSZ);

    // 3. Attention -> res [b][384][1024] bf16
    attn_mfma<<<dim3(8, NH, BATCH), 512, 0, stream>>>(qkT, vo, res);

    // 4. gated = (res + lepe(v)) * o
    lepe_mul<<<dim3(DIM, BATCH), 256, 0, stream>>>(vo, lepe_w, lepe_b, res, gated);

    // 5. gated -> gatedT [b][1024][384] bf16
    tcast_b16<<<dim3(32, 12, BATCH), 256, 0, stream>>>(gated, gatedT, DIM, HWSZ);

    // 6. proj GEMM -> out f32
    gemm_mfma<1><<<dim3(8, 3, BATCH), 256, 0, stream>>>(
        wpb, gatedT, proj_b, nullptr, nullptr, (float*)d_out, DIM, DIM, HWSZ);
}

// Round 10
// 181.650 us; speedup vs baseline: 1.1921x; 1.1921x over previous
//
#include <hip/hip_runtime.h>
#include <hip/hip_bf16.h>

#define DIM   384
#define NH    12
#define HD    32
#define HWSZ  1024
#define BATCH 8
#define SCALE 0.17677669529663687f          // 32^-0.5
#define EXP_K (SCALE * 1.4426950408889634f) // SCALE * log2(e): q pre-scale for exp2

typedef __attribute__((ext_vector_type(8))) short bf16x8;
typedef __attribute__((ext_vector_type(4))) float floatx4;

__device__ __forceinline__ unsigned short f2bf(float x) {
    union { __hip_bfloat16 h; unsigned short u; } c;
    c.h = __float2bfloat16(x);          // native v_cvt (RNE)
    return c.u;
}
__device__ __forceinline__ float bf2f(unsigned short h) {
    union { unsigned int u; float f; } v; v.u = ((unsigned int)h) << 16;
    return v.f;
}

// ---------------------------------------------------------------------------
// Weight pre-cast: qkvo_w (1536x384) and proj_w (384x384) f32 -> bf16, once.
// ---------------------------------------------------------------------------
__global__ __launch_bounds__(256) void cast_w(
    const float* __restrict__ wa, const float* __restrict__ wb,
    unsigned short* __restrict__ da, unsigned short* __restrict__ db, int na8)
{
    const int idx = blockIdx.x * 256 + threadIdx.x;
    const float* src; unsigned short* dst; int i;
    if (idx < na8) { src = wa; dst = da; i = idx; }
    else           { src = wb; dst = db; i = idx - na8; }
    float4 f0 = *(const float4*)&src[i * 8];
    float4 f1 = *(const float4*)&src[i * 8 + 4];
    ushort4 h0 = make_ushort4(f2bf(f0.x), f2bf(f0.y), f2bf(f0.z), f2bf(f0.w));
    ushort4 h1 = make_ushort4(f2bf(f1.x), f2bf(f1.y), f2bf(f1.z), f2bf(f1.w));
    *(ushort4*)&dst[i * 8] = h0;
    *(ushort4*)&dst[i * 8 + 4] = h1;
}

// ---------------------------------------------------------------------------
// Transpose+cast: in [B][C][N] f32 -> out [B][N][C] bf16.  grid(N/32, C/32, B)
// ---------------------------------------------------------------------------
__global__ __launch_bounds__(256) void tcast_f32(
    const float* __restrict__ in, unsigned short* __restrict__ out, int C, int N)
{
    __shared__ __align__(16) unsigned short t[32][36];
    const int n0 = blockIdx.x * 32, c0 = blockIdx.y * 32, b = blockIdx.z;
    const float* ib = in + (size_t)b * C * N;
    unsigned short* ob = out + (size_t)b * N * C;
    const int tid = threadIdx.x;
    const int r = tid >> 3, q = (tid & 7) * 4;
    float4 f = *(const float4*)&ib[(size_t)(c0 + r) * N + n0 + q];
    ushort4 h = make_ushort4(f2bf(f.x), f2bf(f.y), f2bf(f.z), f2bf(f.w));
    *(ushort4*)&t[r][q] = h;
    __syncthreads();
    ushort4 o;
    o.x = t[q + 0][r]; o.y = t[q + 1][r]; o.z = t[q + 2][r]; o.w = t[q + 3][r];
    *(ushort4*)&ob[(size_t)(n0 + r) * C + c0 + q] = o;
}

// Same, bf16 input.
__global__ __launch_bounds__(256) void tcast_b16(
    const unsigned short* __restrict__ in, unsigned short* __restrict__ out, int C, int N)
{
    __shared__ __align__(16) unsigned short t[32][36];
    const int n0 = blockIdx.x * 32, c0 = blockIdx.y * 32, b = blockIdx.z;
    const unsigned short* ib = in + (size_t)b * C * N;
    unsigned short* ob = out + (size_t)b * N * C;
    const int tid = threadIdx.x;
    const int r = tid >> 3, q = (tid & 7) * 4;
    ushort4 h = *(const ushort4*)&ib[(size_t)(c0 + r) * N + n0 + q];
    *(ushort4*)&t[r][q] = h;
    __syncthreads();
    ushort4 o;
    o.x = t[q + 0][r]; o.y = t[q + 1][r]; o.z = t[q + 2][r]; o.w = t[q + 3][r];
    *(ushort4*)&ob[(size_t)(n0 + r) * C + c0 + q] = o;
}

// ---------------------------------------------------------------------------
// MFMA GEMM, 128x128 tile, BK=32, 256 threads = 4 waves (2x2 wave grid).
// Wave owns a 64x64 quadrant = 4x4 16x16 frags -> 16 MFMA per k-step.
// Y[b][m][n] = sum_k Wb16[m][k]*Xt[b][n][k] + bias[m]
// MODE 0 (qkvo): m0<768 -> qkT[b][n][m] (q pre-scaled by EXP_K), via LDS-staged
//                coalesced epilogue (Cs[n][m]);
//                m0>=768 -> vo[b][m-768][n] via SWAPPED-operand MFMA (register
//                quad runs along n) + LDS-staged epilogue (Cs[m][n]).
// MODE 1 (proj): Yf[b][m][n] f32 direct stores.
// ---------------------------------------------------------------------------
template<int MODE>
__global__ __launch_bounds__(256) void gemm_mfma(
    const unsigned short* __restrict__ Wb16, const unsigned short* __restrict__ Xt,
    const float* __restrict__ bias, unsigned short* __restrict__ qkT,
    unsigned short* __restrict__ vo, float* __restrict__ Yf,
    int M, int K, int N)
{
    // Aliased LDS: staging As[128][40]+Bs[128][40] (20.5KB) vs epilogue
    // Cs[128][132] (33.8KB).
    __shared__ __align__(16) unsigned short lds[16896];
    #define AS(r, k) lds[(r) * 40 + (k)]
    #define BS(r, k) lds[5120 + (r) * 40 + (k)]
    #define CS(r, c2) lds[(r) * 132 + (c2)]

    const int b = blockIdx.z, m0 = blockIdx.y * 128, n0 = blockIdx.x * 128;
    const int tid = threadIdx.x;
    const int w = tid >> 6, lane = tid & 63;
    const int wr = w >> 1, wc = w & 1;
    const int g = lane >> 4, c = lane & 15;

    const bool SWAPPED = (MODE == 0) && (m0 >= 768);

    const unsigned short* Xb = Xt + (size_t)b * N * K;

    floatx4 acc[4][4];
    #pragma unroll
    for (int i = 0; i < 4; ++i)
        #pragma unroll
        for (int j = 0; j < 4; ++j) acc[i][j] = (floatx4){0.f, 0.f, 0.f, 0.f};

    const int srow = tid >> 1, shh = (tid & 1) * 16;   // staging coords

    for (int k0 = 0; k0 < K; k0 += 32) {
        __syncthreads();
        {
            const unsigned short* wp = &Wb16[(size_t)(m0 + srow) * K + k0 + shh];
            *(bf16x8*)&AS(srow, shh)     = *(const bf16x8*)wp;
            *(bf16x8*)&AS(srow, shh + 8) = *(const bf16x8*)(wp + 8);
            const unsigned short* xp = &Xb[(size_t)(n0 + srow) * K + k0 + shh];
            *(bf16x8*)&BS(srow, shh)     = *(const bf16x8*)xp;
            *(bf16x8*)&BS(srow, shh + 8) = *(const bf16x8*)(xp + 8);
        }
        __syncthreads();

        bf16x8 af[4], bfj[4];
        #pragma unroll
        for (int i = 0; i < 4; ++i)
            af[i] = *(const bf16x8*)&AS(64 * wr + 16 * i + c, 8 * g);
        #pragma unroll
        for (int j = 0; j < 4; ++j)
            bfj[j] = *(const bf16x8*)&BS(64 * wc + 16 * j + c, 8 * g);
        if (!SWAPPED) {
            #pragma unroll
            for (int i = 0; i < 4; ++i)
                #pragma unroll
                for (int j = 0; j < 4; ++j)
                    acc[i][j] = __builtin_amdgcn_mfma_f32_16x16x32_bf16(
                        af[i], bfj[j], acc[i][j], 0, 0, 0);
        } else {
            #pragma unroll
            for (int i = 0; i < 4; ++i)
                #pragma unroll
                for (int j = 0; j < 4; ++j)
                    acc[i][j] = __builtin_amdgcn_mfma_f32_16x16x32_bf16(
                        bfj[j], af[i], acc[i][j], 0, 0, 0);
        }
    }

    if (MODE == 1) {
        // proj: normal mapping D[m=m0+64wr+16i+4g+r][n=n0+64wc+16j+c], f32 out
        #pragma unroll
        for (int i = 0; i < 4; ++i) {
            const int m = m0 + 64 * wr + 16 * i + 4 * g;
            float bi[4];
            #pragma unroll
            for (int r = 0; r < 4; ++r) bi[r] = bias[m + r];
            #pragma unroll
            for (int j = 0; j < 4; ++j) {
                const int n = n0 + 64 * wc + 16 * j + c;
                #pragma unroll
                for (int r = 0; r < 4; ++r)
                    Yf[((size_t)b * M + m + r) * (size_t)N + n] = acc[i][j][r] + bi[r];
            }
        }
        return;
    }

    __syncthreads();   // staging readers done; safe to overwrite lds with Cs

    if (m0 < 768) {
        // q/k: normal mapping; Cs[n_local][m_local], quad along m (ushort4)
        const float qs = (m0 < 384) ? EXP_K : 1.0f;
        #pragma unroll
        for (int i = 0; i < 4; ++i) {
            const int mb = 64 * wr + 16 * i + 4 * g;
            float bi[4];
            #pragma unroll
            for (int r = 0; r < 4; ++r) bi[r] = bias[m0 + mb + r];
            #pragma unroll
            for (int j = 0; j < 4; ++j) {
                const int nl = 64 * wc + 16 * j + c;
                ushort4 h;
                h.x = f2bf((acc[i][j][0] + bi[0]) * qs);
                h.y = f2bf((acc[i][j][1] + bi[1]) * qs);
                h.z = f2bf((acc[i][j][2] + bi[2]) * qs);
                h.w = f2bf((acc[i][j][3] + bi[3]) * qs);
                *(ushort4*)&CS(nl, mb) = h;
            }
        }
        __syncthreads();
        // Coalesced: row n -> qkT[b][n0+n][m0..m0+128] (256B contiguous)
        const int rl = tid >> 1, half = (tid & 1) * 64;
        unsigned short* dst = &qkT[((size_t)b * HWSZ + n0 + rl) * 768 + m0 + half];
        const unsigned short* src = &CS(rl, half);
        #pragma unroll
        for (int u = 0; u < 8; ++u)
            *(bf16x8*)(dst + 8 * u) = *(const bf16x8*)(src + 8 * u);
    } else {
        // v/o: swapped mapping D[n=n0+64wc+16j+4g+r][m=m0+64wr+16i+c];
        // Cs[m_local][n_local], quad along n (ushort4)
        #pragma unroll
        for (int i = 0; i < 4; ++i) {
            const int ml = 64 * wr + 16 * i + c;
            const float bi = bias[m0 + ml];
            #pragma unroll
            for (int j = 0; j < 4; ++j) {
                const int nb = 64 * wc + 16 * j + 4 * g;
                ushort4 h;
                h.x = f2bf(acc[i][j][0] + bi);
                h.y = f2bf(acc[i][j][1] + bi);
                h.z = f2bf(acc[i][j][2] + bi);
                h.w = f2bf(acc[i][j][3] + bi);
                *(ushort4*)&CS(ml, nb) = h;
            }
        }
        __syncthreads();
        // Coalesced: row m -> vo[b][m0-768+m][n0..n0+128] (256B contiguous)
        const int rl = tid >> 1, half = (tid & 1) * 64;
        unsigned short* dst =
            &vo[((size_t)b * 768 + (m0 - 768) + rl) * HWSZ + n0 + half];
        const unsigned short* src = &CS(rl, half);
        #pragma unroll
        for (int u = 0; u < 8; ++u)
            *(bf16x8*)(dst + 8 * u) = *(const bf16x8*)(src + 8 * u);
    }
    #undef AS
    #undef BS
    #undef CS
}

// ---------------------------------------------------------------------------
// MFMA attention (round-4 validated version). Block = (b, head h, 128 p-rows);
// 8 waves, wave w owns 16 p. q pre-scaled by EXP_K -> P = exp2(st) directly.
// Swapped QK^T: St = mfma(K-frag, Q-frag) -> lane holds St[j=jb*16+4g+r][p=16w+c].
// P packed bf16 -> Ps[p][j] (same-wave only). PV: O = mfma(P-frag, V^T-frag);
// normalize by 1/l at the end (flash linearity, no max-subtraction).
// ---------------------------------------------------------------------------
__global__ __launch_bounds__(512) void attn_mfma(
    const unsigned short* __restrict__ qkT, const unsigned short* __restrict__ vo,
    unsigned short* __restrict__ res)
{
    __shared__ __align__(16) unsigned short Ks[64][40];   // [j][d]
    __shared__ __align__(16) unsigned short Vs[32][72];   // [d][j]
    __shared__ __align__(16) unsigned short Ps[128][72];  // [p][j]
    __shared__ float lbuf[128];

    const int b = blockIdx.z, h = blockIdx.y, p0 = blockIdx.x * 128;
    const int tid = threadIdx.x;
    const int w = tid >> 6, lane = tid & 63;
    const int g = lane >> 4, c = lane & 15;

    const unsigned short* qkTb = qkT + (size_t)b * HWSZ * 768;
    const unsigned short* vb   = vo + ((size_t)b * 768 + h * HD) * HWSZ;

    // Q B-frag (hoisted): col p = p0+16w+c, k d = 8g+i
    bf16x8 qf = *(const bf16x8*)&qkTb[(size_t)(p0 + 16 * w + c) * 768 + h * HD + 8 * g];

    floatx4 oacc0 = (floatx4){0.f, 0.f, 0.f, 0.f};
    floatx4 oacc1 = (floatx4){0.f, 0.f, 0.f, 0.f};
    float Lacc = 0.f;

    for (int j0 = 0; j0 < HWSZ; j0 += 64) {
        __syncthreads();
        if (tid < 256) {
            const int jr = tid >> 2, d8 = (tid & 3) * 8;
            *(bf16x8*)&Ks[jr][d8] =
                *(const bf16x8*)&qkTb[(size_t)(j0 + jr) * 768 + 384 + h * HD + d8];
        } else {
            const int t = tid - 256;
            const int dr = t >> 3, j8 = (t & 7) * 8;
            *(bf16x8*)&Vs[dr][j8] =
                *(const bf16x8*)&vb[(size_t)dr * HWSZ + j0 + j8];
        }
        __syncthreads();

        // QK^T (swapped) + exp2 + pack into Ps
        #pragma unroll
        for (int jb = 0; jb < 4; ++jb) {
            bf16x8 kf = *(const bf16x8*)&Ks[jb * 16 + c][8 * g];
            floatx4 st = (floatx4){0.f, 0.f, 0.f, 0.f};
            st = __builtin_amdgcn_mfma_f32_16x16x32_bf16(kf, qf, st, 0, 0, 0);
            float e0 = exp2f(st[0]);
            float e1 = exp2f(st[1]);
            float e2 = exp2f(st[2]);
            float e3 = exp2f(st[3]);
            Lacc += (e0 + e1) + (e2 + e3);
            ushort4 pe = make_ushort4(f2bf(e0), f2bf(e1), f2bf(e2), f2bf(e3));
            *(ushort4*)&Ps[16 * w + c][jb * 16 + 4 * g] = pe;
        }

        // PV: A = own wave's Ps rows, B = V^T from Vs
        #pragma unroll
        for (int jk = 0; jk < 2; ++jk) {
            bf16x8 pf  = *(const bf16x8*)&Ps[16 * w + c][jk * 32 + 8 * g];
            bf16x8 vf0 = *(const bf16x8*)&Vs[c][jk * 32 + 8 * g];
            bf16x8 vf1 = *(const bf16x8*)&Vs[16 + c][jk * 32 + 8 * g];
            oacc0 = __builtin_amdgcn_mfma_f32_16x16x32_bf16(pf, vf0, oacc0, 0, 0, 0);
            oacc1 = __builtin_amdgcn_mfma_f32_16x16x32_bf16(pf, vf1, oacc1, 0, 0, 0);
        }
    }

    // Row sums l[p]: lane has partial for p=16w+c over its j-subset; reduce over g
    Lacc += __shfl_xor(Lacc, 16, 64);
    Lacc += __shfl_xor(Lacc, 32, 64);
    if (g == 0) lbuf[16 * w + c] = Lacc;   // same-wave producer/consumer

    float linv[4];
    #pragma unroll
    for (int r = 0; r < 4; ++r) linv[r] = 1.0f / lbuf[16 * w + 4 * g + r];

    // O D-frag: lane holds O[p = p0+16w+4g+r][d = dblk*16+c]; 4 consecutive p -> 8B
    unsigned short* rp = res + ((size_t)b * DIM + h * HD) * HWSZ;
    const int pbase = p0 + 16 * w + 4 * g;
    ushort4 h0, h1;
    h0.x = f2bf(oacc0[0] * linv[0]); h0.y = f2bf(oacc0[1] * linv[1]);
    h0.z = f2bf(oacc0[2] * linv[2]); h0.w = f2bf(oacc0[3] * linv[3]);
    h1.x = f2bf(oacc1[0] * linv[0]); h1.y = f2bf(oacc1[1] * linv[1]);
    h1.z = f2bf(oacc1[2] * linv[2]); h1.w = f2bf(oacc1[3] * linv[3]);
    *(ushort4*)&rp[(size_t)c * HWSZ + pbase] = h0;
    *(ushort4*)&rp[(size_t)(16 + c) * HWSZ + pbase] = h1;
}

// ---------------------------------------------------------------------------
// LePE 5x5 depthwise on v + bias, fused gate: gated = (res + lepe(v)) * o.
// ---------------------------------------------------------------------------
__global__ __launch_bounds__(256) void lepe_mul(
    const unsigned short* __restrict__ vo, const float* __restrict__ lw,
    const float* __restrict__ lb, const unsigned short* __restrict__ res,
    unsigned short* __restrict__ gated)
{
    const int cch = blockIdx.x, b = blockIdx.y;
    const unsigned short* v  = vo + ((size_t)b * 768 + cch) * HWSZ;
    const unsigned short* o  = vo + ((size_t)b * 768 + 384 + cch) * HWSZ;
    const unsigned short* rp = res + ((size_t)b * DIM + cch) * HWSZ;
    unsigned short* gp = gated + ((size_t)b * DIM + cch) * HWSZ;

    __shared__ float vs[1024];
    __shared__ float wgt[25];

    const int tid = threadIdx.x;
    {
        ushort4 hv = *(const ushort4*)&v[tid * 4];
        vs[tid * 4 + 0] = bf2f(hv.x); vs[tid * 4 + 1] = bf2f(hv.y);
        vs[tid * 4 + 2] = bf2f(hv.z); vs[tid * 4 + 3] = bf2f(hv.w);
    }
    if (tid < 25) wgt[tid] = lw[cch * 25 + tid];
    __syncthreads();

    const float bias = lb[cch];
    const int q0 = tid * 4;
    const int y  = q0 >> 5;
    const int x0 = q0 & 31;

    float acc[4] = {bias, bias, bias, bias};
    #pragma unroll
    for (int ky = 0; ky < 5; ++ky) {
        int iy = y + ky - 2;
        if ((unsigned)iy < 32u) {
            #pragma unroll
            for (int kx = 0; kx < 5; ++kx) {
                float wv = wgt[ky * 5 + kx];
                #pragma unroll
                for (int u = 0; u < 4; ++u) {
                    int ix = x0 + u + kx - 2;
                    if ((unsigned)ix < 32u) acc[u] += wv * vs[iy * 32 + ix];
                }
            }
        }
    }

    ushort4 rh = *(const ushort4*)&rp[q0];
    ushort4 oh = *(const ushort4*)&o[q0];
    ushort4 outv;
    outv.x = f2bf((bf2f(rh.x) + acc[0]) * bf2f(oh.x));
    outv.y = f2bf((bf2f(rh.y) + acc[1]) * bf2f(oh.y));
    outv.z = f2bf((bf2f(rh.z) + acc[2]) * bf2f(oh.z));
    outv.w = f2bf((bf2f(rh.w) + acc[3]) * bf2f(oh.w));
    *(ushort4*)&gp[q0] = outv;
}

// ---------------------------------------------------------------------------
extern "C" void kernel_launch(void* const* d_in, const int* in_sizes, int n_in,
                              void* d_out, int out_size, void* d_ws, size_t ws_size,
                              hipStream_t stream)
{
    const float* x      = (const float*)d_in[0];
    const float* qkvo_w = (const float*)d_in[1];
    const float* qkvo_b = (const float*)d_in[2];
    const float* lepe_w = (const float*)d_in[3];
    const float* lepe_b = (const float*)d_in[4];
    const float* proj_w = (const float*)d_in[5];
    const float* proj_b = (const float*)d_in[6];

    unsigned short* xt     = (unsigned short*)d_ws;                    // 8*1024*384
    unsigned short* qkT    = xt     + (size_t)BATCH * HWSZ * DIM;      // 8*1024*768
    unsigned short* vo     = qkT    + (size_t)BATCH * HWSZ * 768;      // 8*768*1024
    unsigned short* res    = vo     + (size_t)BATCH * 768 * HWSZ;      // 8*384*1024
    unsigned short* gated  = res    + (size_t)BATCH * DIM * HWSZ;      // 8*384*1024
    unsigned short* gatedT = gated  + (size_t)BATCH * DIM * HWSZ;      // 8*1024*384
    unsigned short* wqb    = gatedT + (size_t)BATCH * HWSZ * DIM;      // 1536*384
    unsigned short* wpb    = wqb    + (size_t)1536 * DIM;              // 384*384

    // 0. Pre-cast weights to bf16 (na8 = 1536*384/8, nb8 = 384*384/8)
    cast_w<<<dim3((73728 + 18432) / 256), 256, 0, stream>>>(
        qkvo_w, proj_w, wqb, wpb, 73728);

    // 1. x [b][384][1024] f32 -> xt [b][1024][384] bf16
    tcast_f32<<<dim3(32, 12, BATCH), 256, 0, stream>>>(x, xt, DIM, HWSZ);

    // 2. QKVO projection -> qkT (q,k transposed; q pre-scaled) + vo (v,o normal)
    gemm_mfma<0><<<dim3(8, 12, BATCH), 256, 0, stream>>>(
        wqb, xt, qkvo_b, qkT, vo, nullptr, 4 * DIM, DIM, HWSZ);

    // 3. Attention -> res [b][384][1024] bf16
    attn_mfma<<<dim3(8, NH, BATCH), 512, 0, stream>>>(qkT, vo, res);

    // 4. gated = (res + lepe(v)) * o
    lepe_mul<<<dim3(DIM, BATCH), 256, 0, stream>>>(vo, lepe_w, lepe_b, res, gated);

    // 5. gated -> gatedT [b][1024][384] bf16
    tcast_b16<<<dim3(32, 12, BATCH), 256, 0, stream>>>(gated, gatedT, DIM, HWSZ);

    // 6. proj GEMM -> out f32
    gemm_mfma<1><<<dim3(8, 3, BATCH), 256, 0, stream>>>(
        wpb, gatedT, proj_b, nullptr, nullptr, (float*)d_out, DIM, DIM, HWSZ);
}

// Round 11
// 171.331 us; speedup vs baseline: 1.2639x; 1.0602x over previous
//
#include <hip/hip_runtime.h>
#include <hip/hip_bf16.h>

#define DIM   384
#define NH    12
#define HD    32
#define HWSZ  1024
#define BATCH 8
#define SCALE 0.17677669529663687f          // 32^-0.5
#define EXP_K (SCALE * 1.4426950408889634f) // SCALE * log2(e): q pre-scale for exp2

typedef __attribute__((ext_vector_type(8))) short bf16x8;
typedef __attribute__((ext_vector_type(4))) float floatx4;

__device__ __forceinline__ unsigned short f2bf(float x) {
    union { __hip_bfloat16 h; unsigned short u; } c;
    c.h = __float2bfloat16(x);          // native v_cvt (RNE)
    return c.u;
}
__device__ __forceinline__ float bf2f(unsigned short h) {
    union { unsigned int u; float f; } v; v.u = ((unsigned int)h) << 16;
    return v.f;
}

// ---------------------------------------------------------------------------
// Prep: z<8 -> transpose+cast x [B][384][1024] f32 -> xt [B][1024][384] bf16;
//       z==8 -> cast qkvo_w/proj_w f32 -> bf16 (linearized over x,y).
// ---------------------------------------------------------------------------
__global__ __launch_bounds__(256) void prep(
    const float* __restrict__ x, const float* __restrict__ qkvo_w,
    const float* __restrict__ proj_w, unsigned short* __restrict__ xt,
    unsigned short* __restrict__ wqb, unsigned short* __restrict__ wpb)
{
    const int tid = threadIdx.x;
    if (blockIdx.z < 8) {
        __shared__ __align__(16) unsigned short t[32][36];
        const int n0 = blockIdx.x * 32, c0 = blockIdx.y * 32, b = blockIdx.z;
        const float* ib = x + (size_t)b * DIM * HWSZ;
        unsigned short* ob = xt + (size_t)b * HWSZ * DIM;
        const int r = tid >> 3, q = (tid & 7) * 4;
        float4 f = *(const float4*)&ib[(size_t)(c0 + r) * HWSZ + n0 + q];
        ushort4 h = make_ushort4(f2bf(f.x), f2bf(f.y), f2bf(f.z), f2bf(f.w));
        *(ushort4*)&t[r][q] = h;
        __syncthreads();
        ushort4 o;
        o.x = t[q + 0][r]; o.y = t[q + 1][r]; o.z = t[q + 2][r]; o.w = t[q + 3][r];
        *(ushort4*)&ob[(size_t)(n0 + r) * DIM + c0 + q] = o;
    } else {
        const int idx = (blockIdx.y * 32 + blockIdx.x) * 256 + tid;
        if (idx >= 92160) return;          // 73728 + 18432
        const float* src; unsigned short* dst; int i;
        if (idx < 73728) { src = qkvo_w; dst = wqb; i = idx; }
        else             { src = proj_w; dst = wpb; i = idx - 73728; }
        float4 f0 = *(const float4*)&src[i * 8];
        float4 f1 = *(const float4*)&src[i * 8 + 4];
        ushort4 h0 = make_ushort4(f2bf(f0.x), f2bf(f0.y), f2bf(f0.z), f2bf(f0.w));
        ushort4 h1 = make_ushort4(f2bf(f1.x), f2bf(f1.y), f2bf(f1.z), f2bf(f1.w));
        *(ushort4*)&dst[i * 8] = h0;
        *(ushort4*)&dst[i * 8 + 4] = h1;
    }
}

// ---------------------------------------------------------------------------
// Transpose bf16: in [B][C][N] -> out [B][N][C].  grid(N/32, C/32, B)
// ---------------------------------------------------------------------------
__global__ __launch_bounds__(256) void tcast_b16(
    const unsigned short* __restrict__ in, unsigned short* __restrict__ out, int C, int N)
{
    __shared__ __align__(16) unsigned short t[32][36];
    const int n0 = blockIdx.x * 32, c0 = blockIdx.y * 32, b = blockIdx.z;
    const unsigned short* ib = in + (size_t)b * C * N;
    unsigned short* ob = out + (size_t)b * N * C;
    const int tid = threadIdx.x;
    const int r = tid >> 3, q = (tid & 7) * 4;
    ushort4 h = *(const ushort4*)&ib[(size_t)(c0 + r) * N + n0 + q];
    *(ushort4*)&t[r][q] = h;
    __syncthreads();
    ushort4 o;
    o.x = t[q + 0][r]; o.y = t[q + 1][r]; o.z = t[q + 2][r]; o.w = t[q + 3][r];
    *(ushort4*)&ob[(size_t)(n0 + r) * C + c0 + q] = o;
}

// ---------------------------------------------------------------------------
// QKVO GEMM (validated round-10 version): 128x128 tile, BK=32, 4 waves 2x2.
// m0<768 -> qkT[b][n][m] (q pre-scaled), LDS-staged coalesced epilogue;
// m0>=768 -> vo[b][m-768][n] via swapped-operand MFMA + staged epilogue.
// ---------------------------------------------------------------------------
__global__ __launch_bounds__(256) void gemm_qkvo(
    const unsigned short* __restrict__ Wb16, const unsigned short* __restrict__ Xt,
    const float* __restrict__ bias, unsigned short* __restrict__ qkT,
    unsigned short* __restrict__ vo)
{
    __shared__ __align__(16) unsigned short lds[16896];
    #define AS(r, k) lds[(r) * 40 + (k)]
    #define BS(r, k) lds[5120 + (r) * 40 + (k)]
    #define CS(r, c2) lds[(r) * 132 + (c2)]

    const int b = blockIdx.z, m0 = blockIdx.y * 128, n0 = blockIdx.x * 128;
    const int tid = threadIdx.x;
    const int w = tid >> 6, lane = tid & 63;
    const int wr = w >> 1, wc = w & 1;
    const int g = lane >> 4, c = lane & 15;
    const bool SWAPPED = (m0 >= 768);

    const unsigned short* Xb = Xt + (size_t)b * HWSZ * DIM;

    floatx4 acc[4][4];
    #pragma unroll
    for (int i = 0; i < 4; ++i)
        #pragma unroll
        for (int j = 0; j < 4; ++j) acc[i][j] = (floatx4){0.f, 0.f, 0.f, 0.f};

    const int srow = tid >> 1, shh = (tid & 1) * 16;

    for (int k0 = 0; k0 < DIM; k0 += 32) {
        __syncthreads();
        {
            const unsigned short* wp = &Wb16[(size_t)(m0 + srow) * DIM + k0 + shh];
            *(bf16x8*)&AS(srow, shh)     = *(const bf16x8*)wp;
            *(bf16x8*)&AS(srow, shh + 8) = *(const bf16x8*)(wp + 8);
            const unsigned short* xp = &Xb[(size_t)(n0 + srow) * DIM + k0 + shh];
            *(bf16x8*)&BS(srow, shh)     = *(const bf16x8*)xp;
            *(bf16x8*)&BS(srow, shh + 8) = *(const bf16x8*)(xp + 8);
        }
        __syncthreads();

        bf16x8 af[4], bfj[4];
        #pragma unroll
        for (int i = 0; i < 4; ++i)
            af[i] = *(const bf16x8*)&AS(64 * wr + 16 * i + c, 8 * g);
        #pragma unroll
        for (int j = 0; j < 4; ++j)
            bfj[j] = *(const bf16x8*)&BS(64 * wc + 16 * j + c, 8 * g);
        if (!SWAPPED) {
            #pragma unroll
            for (int i = 0; i < 4; ++i)
                #pragma unroll
                for (int j = 0; j < 4; ++j)
                    acc[i][j] = __builtin_amdgcn_mfma_f32_16x16x32_bf16(
                        af[i], bfj[j], acc[i][j], 0, 0, 0);
        } else {
            #pragma unroll
            for (int i = 0; i < 4; ++i)
                #pragma unroll
                for (int j = 0; j < 4; ++j)
                    acc[i][j] = __builtin_amdgcn_mfma_f32_16x16x32_bf16(
                        bfj[j], af[i], acc[i][j], 0, 0, 0);
        }
    }

    __syncthreads();   // staging readers done; reuse lds as Cs

    if (m0 < 768) {
        const float qs = (m0 < 384) ? EXP_K : 1.0f;
        #pragma unroll
        for (int i = 0; i < 4; ++i) {
            const int mb = 64 * wr + 16 * i + 4 * g;
            float bi[4];
            #pragma unroll
            for (int r = 0; r < 4; ++r) bi[r] = bias[m0 + mb + r];
            #pragma unroll
            for (int j = 0; j < 4; ++j) {
                const int nl = 64 * wc + 16 * j + c;
                ushort4 h;
                h.x = f2bf((acc[i][j][0] + bi[0]) * qs);
                h.y = f2bf((acc[i][j][1] + bi[1]) * qs);
                h.z = f2bf((acc[i][j][2] + bi[2]) * qs);
                h.w = f2bf((acc[i][j][3] + bi[3]) * qs);
                *(ushort4*)&CS(nl, mb) = h;
            }
        }
        __syncthreads();
        const int rl = tid >> 1, half = (tid & 1) * 64;
        unsigned short* dst = &qkT[((size_t)b * HWSZ + n0 + rl) * 768 + m0 + half];
        const unsigned short* src = &CS(rl, half);
        #pragma unroll
        for (int u = 0; u < 8; ++u)
            *(bf16x8*)(dst + 8 * u) = *(const bf16x8*)(src + 8 * u);
    } else {
        #pragma unroll
        for (int i = 0; i < 4; ++i) {
            const int ml = 64 * wr + 16 * i + c;
            const float bi = bias[m0 + ml];
            #pragma unroll
            for (int j = 0; j < 4; ++j) {
                const int nb = 64 * wc + 16 * j + 4 * g;
                ushort4 h;
                h.x = f2bf(acc[i][j][0] + bi);
                h.y = f2bf(acc[i][j][1] + bi);
                h.z = f2bf(acc[i][j][2] + bi);
                h.w = f2bf(acc[i][j][3] + bi);
                *(ushort4*)&CS(ml, nb) = h;
            }
        }
        __syncthreads();
        const int rl = tid >> 1, half = (tid & 1) * 64;
        unsigned short* dst =
            &vo[((size_t)b * 768 + (m0 - 768) + rl) * HWSZ + n0 + half];
        const unsigned short* src = &CS(rl, half);
        #pragma unroll
        for (int u = 0; u < 8; ++u)
            *(bf16x8*)(dst + 8 * u) = *(const bf16x8*)(src + 8 * u);
    }
    #undef AS
    #undef BS
    #undef CS
}

// ---------------------------------------------------------------------------
// Proj GEMM: 64x64 tile, BK=32, 4 waves 2x2 (wave quadrant 32x32 = 2x2 frags).
// Grid (16,6,8)=768 blocks -> 3 blocks/CU (fixes <1 block/CU under-occupancy).
// Yf[b][m][n] = sum_k Wb16[m][k]*Xt[b][n][k] + bias[m], f32 out.
// ---------------------------------------------------------------------------
__global__ __launch_bounds__(256) void gemm_proj(
    const unsigned short* __restrict__ Wb16, const unsigned short* __restrict__ Xt,
    const float* __restrict__ bias, float* __restrict__ Yf)
{
    __shared__ __align__(16) unsigned short As[64][40];
    __shared__ __align__(16) unsigned short Bs[64][40];

    const int b = blockIdx.z, m0 = blockIdx.y * 64, n0 = blockIdx.x * 64;
    const int tid = threadIdx.x;
    const int w = tid >> 6, lane = tid & 63;
    const int wr = w >> 1, wc = w & 1;
    const int g = lane >> 4, c = lane & 15;

    const unsigned short* Xb = Xt + (size_t)b * HWSZ * DIM;

    floatx4 acc[2][2];
    #pragma unroll
    for (int i = 0; i < 2; ++i)
        #pragma unroll
        for (int j = 0; j < 2; ++j) acc[i][j] = (floatx4){0.f, 0.f, 0.f, 0.f};

    const int srow = tid >> 2, sk8 = (tid & 3) * 8;

    for (int k0 = 0; k0 < DIM; k0 += 32) {
        __syncthreads();
        *(bf16x8*)&As[srow][sk8] =
            *(const bf16x8*)&Wb16[(size_t)(m0 + srow) * DIM + k0 + sk8];
        *(bf16x8*)&Bs[srow][sk8] =
            *(const bf16x8*)&Xb[(size_t)(n0 + srow) * DIM + k0 + sk8];
        __syncthreads();

        bf16x8 af[2], bfj[2];
        #pragma unroll
        for (int i = 0; i < 2; ++i)
            af[i] = *(const bf16x8*)&As[32 * wr + 16 * i + c][8 * g];
        #pragma unroll
        for (int j = 0; j < 2; ++j)
            bfj[j] = *(const bf16x8*)&Bs[32 * wc + 16 * j + c][8 * g];
        #pragma unroll
        for (int i = 0; i < 2; ++i)
            #pragma unroll
            for (int j = 0; j < 2; ++j)
                acc[i][j] = __builtin_amdgcn_mfma_f32_16x16x32_bf16(
                    af[i], bfj[j], acc[i][j], 0, 0, 0);
    }

    #pragma unroll
    for (int i = 0; i < 2; ++i) {
        const int m = m0 + 32 * wr + 16 * i + 4 * g;
        float bi[4];
        #pragma unroll
        for (int r = 0; r < 4; ++r) bi[r] = bias[m + r];
        #pragma unroll
        for (int j = 0; j < 2; ++j) {
            const int n = n0 + 32 * wc + 16 * j + c;
            #pragma unroll
            for (int r = 0; r < 4; ++r)
                Yf[((size_t)b * DIM + m + r) * (size_t)HWSZ + n] = acc[i][j][r] + bi[r];
        }
    }
}

// ---------------------------------------------------------------------------
// MFMA attention. Block = (b, head h, 128 p-rows); 8 waves, wave owns 16 p.
// q pre-scaled by EXP_K -> P = exp2(st). Swapped QK^T; P bf16 -> Ps (same-wave).
// Row sums via ones-MFMA: lacc = mfma(pf, ones, lacc) -> l in the SAME frag
// layout as oacc rows; no shuffles, no lbuf. Normalize at end.
// ---------------------------------------------------------------------------
__global__ __launch_bounds__(512) void attn_mfma(
    const unsigned short* __restrict__ qkT, const unsigned short* __restrict__ vo,
    unsigned short* __restrict__ res)
{
    __shared__ __align__(16) unsigned short Ks[64][40];   // [j][d]
    __shared__ __align__(16) unsigned short Vs[32][72];   // [d][j]
    __shared__ __align__(16) unsigned short Ps[128][72];  // [p][j]

    const int b = blockIdx.z, h = blockIdx.y, p0 = blockIdx.x * 128;
    const int tid = threadIdx.x;
    const int w = tid >> 6, lane = tid & 63;
    const int g = lane >> 4, c = lane & 15;

    const unsigned short* qkTb = qkT + (size_t)b * HWSZ * 768;
    const unsigned short* vb   = vo + ((size_t)b * 768 + h * HD) * HWSZ;

    // Q B-frag (hoisted): col p = p0+16w+c, k d = 8g+i
    bf16x8 qf = *(const bf16x8*)&qkTb[(size_t)(p0 + 16 * w + c) * 768 + h * HD + 8 * g];

    const bf16x8 onesf = {0x3F80, 0x3F80, 0x3F80, 0x3F80,
                          0x3F80, 0x3F80, 0x3F80, 0x3F80};  // bf16 1.0 x8

    floatx4 oacc0 = (floatx4){0.f, 0.f, 0.f, 0.f};
    floatx4 oacc1 = (floatx4){0.f, 0.f, 0.f, 0.f};
    floatx4 lacc  = (floatx4){0.f, 0.f, 0.f, 0.f};

    for (int j0 = 0; j0 < HWSZ; j0 += 64) {
        __syncthreads();
        if (tid < 256) {
            const int jr = tid >> 2, d8 = (tid & 3) * 8;
            *(bf16x8*)&Ks[jr][d8] =
                *(const bf16x8*)&qkTb[(size_t)(j0 + jr) * 768 + 384 + h * HD + d8];
        } else {
            const int t = tid - 256;
            const int dr = t >> 3, j8 = (t & 7) * 8;
            *(bf16x8*)&Vs[dr][j8] =
                *(const bf16x8*)&vb[(size_t)dr * HWSZ + j0 + j8];
        }
        __syncthreads();

        // QK^T (swapped) + exp2 + pack into Ps
        #pragma unroll
        for (int jb = 0; jb < 4; ++jb) {
            bf16x8 kf = *(const bf16x8*)&Ks[jb * 16 + c][8 * g];
            floatx4 st = (floatx4){0.f, 0.f, 0.f, 0.f};
            st = __builtin_amdgcn_mfma_f32_16x16x32_bf16(kf, qf, st, 0, 0, 0);
            ushort4 pe = make_ushort4(f2bf(exp2f(st[0])), f2bf(exp2f(st[1])),
                                      f2bf(exp2f(st[2])), f2bf(exp2f(st[3])));
            *(ushort4*)&Ps[16 * w + c][jb * 16 + 4 * g] = pe;
        }

        // PV + row-sum: A = own wave's Ps rows; B = V^T / ones
        #pragma unroll
        for (int jk = 0; jk < 2; ++jk) {
            bf16x8 pf  = *(const bf16x8*)&Ps[16 * w + c][jk * 32 + 8 * g];
            bf16x8 vf0 = *(const bf16x8*)&Vs[c][jk * 32 + 8 * g];
            bf16x8 vf1 = *(const bf16x8*)&Vs[16 + c][jk * 32 + 8 * g];
            oacc0 = __builtin_amdgcn_mfma_f32_16x16x32_bf16(pf, vf0, oacc0, 0, 0, 0);
            oacc1 = __builtin_amdgcn_mfma_f32_16x16x32_bf16(pf, vf1, oacc1, 0, 0, 0);
            lacc  = __builtin_amdgcn_mfma_f32_16x16x32_bf16(pf, onesf, lacc, 0, 0, 0);
        }
    }

    // lacc[r] = l[p = p0+16w+4g+r] (every col identical) — matches oacc rows.
    float linv[4];
    #pragma unroll
    for (int r = 0; r < 4; ++r) linv[r] = 1.0f / lacc[r];

    unsigned short* rp = res + ((size_t)b * DIM + h * HD) * HWSZ;
    const int pbase = p0 + 16 * w + 4 * g;
    ushort4 h0, h1;
    h0.x = f2bf(oacc0[0] * linv[0]); h0.y = f2bf(oacc0[1] * linv[1]);
    h0.z = f2bf(oacc0[2] * linv[2]); h0.w = f2bf(oacc0[3] * linv[3]);
    h1.x = f2bf(oacc1[0] * linv[0]); h1.y = f2bf(oacc1[1] * linv[1]);
    h1.z = f2bf(oacc1[2] * linv[2]); h1.w = f2bf(oacc1[3] * linv[3]);
    *(ushort4*)&rp[(size_t)c * HWSZ + pbase] = h0;
    *(ushort4*)&rp[(size_t)(16 + c) * HWSZ + pbase] = h1;
}

// ---------------------------------------------------------------------------
// LePE 5x5 depthwise on v + bias, fused gate: gated = (res + lepe(v)) * o.
// ---------------------------------------------------------------------------
__global__ __launch_bounds__(256) void lepe_mul(
    const unsigned short* __restrict__ vo, const float* __restrict__ lw,
    const float* __restrict__ lb, const unsigned short* __restrict__ res,
    unsigned short* __restrict__ gated)
{
    const int cch = blockIdx.x, b = blockIdx.y;
    const unsigned short* v  = vo + ((size_t)b * 768 + cch) * HWSZ;
    const unsigned short* o  = vo + ((size_t)b * 768 + 384 + cch) * HWSZ;
    const unsigned short* rp = res + ((size_t)b * DIM + cch) * HWSZ;
    unsigned short* gp = gated + ((size_t)b * DIM + cch) * HWSZ;

    __shared__ float vs[1024];
    __shared__ float wgt[25];

    const int tid = threadIdx.x;
    {
        ushort4 hv = *(const ushort4*)&v[tid * 4];
        vs[tid * 4 + 0] = bf2f(hv.x); vs[tid * 4 + 1] = bf2f(hv.y);
        vs[tid * 4 + 2] = bf2f(hv.z); vs[tid * 4 + 3] = bf2f(hv.w);
    }
    if (tid < 25) wgt[tid] = lw[cch * 25 + tid];
    __syncthreads();

    const float bias = lb[cch];
    const int q0 = tid * 4;
    const int y  = q0 >> 5;
    const int x0 = q0 & 31;

    float acc[4] = {bias, bias, bias, bias};
    #pragma unroll
    for (int ky = 0; ky < 5; ++ky) {
        int iy = y + ky - 2;
        if ((unsigned)iy < 32u) {
            #pragma unroll
            for (int kx = 0; kx < 5; ++kx) {
                float wv = wgt[ky * 5 + kx];
                #pragma unroll
                for (int u = 0; u < 4; ++u) {
                    int ix = x0 + u + kx - 2;
                    if ((unsigned)ix < 32u) acc[u] += wv * vs[iy * 32 + ix];
                }
            }
        }
    }

    ushort4 rh = *(const ushort4*)&rp[q0];
    ushort4 oh = *(const ushort4*)&o[q0];
    ushort4 outv;
    outv.x = f2bf((bf2f(rh.x) + acc[0]) * bf2f(oh.x));
    outv.y = f2bf((bf2f(rh.y) + acc[1]) * bf2f(oh.y));
    outv.z = f2bf((bf2f(rh.z) + acc[2]) * bf2f(oh.z));
    outv.w = f2bf((bf2f(rh.w) + acc[3]) * bf2f(oh.w));
    *(ushort4*)&gp[q0] = outv;
}

// ---------------------------------------------------------------------------
extern "C" void kernel_launch(void* const* d_in, const int* in_sizes, int n_in,
                              void* d_out, int out_size, void* d_ws, size_t ws_size,
                              hipStream_t stream)
{
    const float* x      = (const float*)d_in[0];
    const float* qkvo_w = (const float*)d_in[1];
    const float* qkvo_b = (const float*)d_in[2];
    const float* lepe_w = (const float*)d_in[3];
    const float* lepe_b = (const float*)d_in[4];
    const float* proj_w = (const float*)d_in[5];
    const float* proj_b = (const float*)d_in[6];

    unsigned short* xt     = (unsigned short*)d_ws;                    // 8*1024*384
    unsigned short* qkT    = xt     + (size_t)BATCH * HWSZ * DIM;      // 8*1024*768
    unsigned short* vo     = qkT    + (size_t)BATCH * HWSZ * 768;      // 8*768*1024
    unsigned short* res    = vo     + (size_t)BATCH * 768 * HWSZ;      // 8*384*1024
    unsigned short* gated  = res    + (size_t)BATCH * DIM * HWSZ;      // 8*384*1024
    unsigned short* gatedT = gated  + (size_t)BATCH * DIM * HWSZ;      // 8*1024*384
    unsigned short* wqb    = gatedT + (size_t)BATCH * HWSZ * DIM;      // 1536*384
    unsigned short* wpb    = wqb    + (size_t)1536 * DIM;              // 384*384

    // 1. prep: x -> xt (transpose+cast) AND weights -> bf16
    prep<<<dim3(32, 12, 9), 256, 0, stream>>>(x, qkvo_w, proj_w, xt, wqb, wpb);

    // 2. QKVO projection -> qkT (q,k transposed; q pre-scaled) + vo
    gemm_qkvo<<<dim3(8, 12, BATCH), 256, 0, stream>>>(wqb, xt, qkvo_b, qkT, vo);

    // 3. Attention -> res [b][384][1024] bf16
    attn_mfma<<<dim3(8, NH, BATCH), 512, 0, stream>>>(qkT, vo, res);

    // 4. gated = (res + lepe(v)) * o
    lepe_mul<<<dim3(DIM, BATCH), 256, 0, stream>>>(vo, lepe_w, lepe_b, res, gated);

    // 5. gated -> gatedT [b][1024][384] bf16
    tcast_b16<<<dim3(32, 12, BATCH), 256, 0, stream>>>(gated, gatedT, DIM, HWSZ);

    // 6. proj GEMM -> out f32 (64x64 tiles, 768 blocks)
    gemm_proj<<<dim3(16, 6, BATCH), 256, 0, stream>>>(wpb, gatedT, proj_b, (float*)d_out);
}

// Round 12
// 169.365 us; speedup vs baseline: 1.2786x; 1.0116x over previous
//
#include <hip/hip_runtime.h>
#include <hip/hip_bf16.h>

#define DIM   384
#define NH    12
#define HD    32
#define HWSZ  1024
#define BATCH 8
#define SCALE 0.17677669529663687f          // 32^-0.5
#define EXP_K (SCALE * 1.4426950408889634f) // SCALE * log2(e): q pre-scale for exp2

typedef __attribute__((ext_vector_type(8))) short bf16x8;
typedef __attribute__((ext_vector_type(4))) float floatx4;

__device__ __forceinline__ unsigned short f2bf(float x) {
    union { __hip_bfloat16 h; unsigned short u; } c;
    c.h = __float2bfloat16(x);          // native v_cvt (RNE)
    return c.u;
}
__device__ __forceinline__ float bf2f(unsigned short h) {
    union { unsigned int u; float f; } v; v.u = ((unsigned int)h) << 16;
    return v.f;
}

// ---------------------------------------------------------------------------
// Prep: z<8 -> transpose+cast x [B][384][1024] f32 -> xt [B][1024][384] bf16;
//       z==8 -> cast qkvo_w/proj_w f32 -> bf16 (linearized over x,y).
// ---------------------------------------------------------------------------
__global__ __launch_bounds__(256) void prep(
    const float* __restrict__ x, const float* __restrict__ qkvo_w,
    const float* __restrict__ proj_w, unsigned short* __restrict__ xt,
    unsigned short* __restrict__ wqb, unsigned short* __restrict__ wpb)
{
    const int tid = threadIdx.x;
    if (blockIdx.z < 8) {
        __shared__ __align__(16) unsigned short t[32][36];
        const int n0 = blockIdx.x * 32, c0 = blockIdx.y * 32, b = blockIdx.z;
        const float* ib = x + (size_t)b * DIM * HWSZ;
        unsigned short* ob = xt + (size_t)b * HWSZ * DIM;
        const int r = tid >> 3, q = (tid & 7) * 4;
        float4 f = *(const float4*)&ib[(size_t)(c0 + r) * HWSZ + n0 + q];
        ushort4 h = make_ushort4(f2bf(f.x), f2bf(f.y), f2bf(f.z), f2bf(f.w));
        *(ushort4*)&t[r][q] = h;
        __syncthreads();
        ushort4 o;
        o.x = t[q + 0][r]; o.y = t[q + 1][r]; o.z = t[q + 2][r]; o.w = t[q + 3][r];
        *(ushort4*)&ob[(size_t)(n0 + r) * DIM + c0 + q] = o;
    } else {
        const int idx = (blockIdx.y * 32 + blockIdx.x) * 256 + tid;
        if (idx >= 92160) return;          // 73728 + 18432
        const float* src; unsigned short* dst; int i;
        if (idx < 73728) { src = qkvo_w; dst = wqb; i = idx; }
        else             { src = proj_w; dst = wpb; i = idx - 73728; }
        float4 f0 = *(const float4*)&src[i * 8];
        float4 f1 = *(const float4*)&src[i * 8 + 4];
        ushort4 h0 = make_ushort4(f2bf(f0.x), f2bf(f0.y), f2bf(f0.z), f2bf(f0.w));
        ushort4 h1 = make_ushort4(f2bf(f1.x), f2bf(f1.y), f2bf(f1.z), f2bf(f1.w));
        *(ushort4*)&dst[i * 8] = h0;
        *(ushort4*)&dst[i * 8 + 4] = h1;
    }
}

// ---------------------------------------------------------------------------
// Transpose bf16: in [B][C][N] -> out [B][N][C].  grid(N/32, C/32, B)
// ---------------------------------------------------------------------------
__global__ __launch_bounds__(256) void tcast_b16(
    const unsigned short* __restrict__ in, unsigned short* __restrict__ out, int C, int N)
{
    __shared__ __align__(16) unsigned short t[32][36];
    const int n0 = blockIdx.x * 32, c0 = blockIdx.y * 32, b = blockIdx.z;
    const unsigned short* ib = in + (size_t)b * C * N;
    unsigned short* ob = out + (size_t)b * N * C;
    const int tid = threadIdx.x;
    const int r = tid >> 3, q = (tid & 7) * 4;
    ushort4 h = *(const ushort4*)&ib[(size_t)(c0 + r) * N + n0 + q];
    *(ushort4*)&t[r][q] = h;
    __syncthreads();
    ushort4 o;
    o.x = t[q + 0][r]; o.y = t[q + 1][r]; o.z = t[q + 2][r]; o.w = t[q + 3][r];
    *(ushort4*)&ob[(size_t)(n0 + r) * C + c0 + q] = o;
}

// ---------------------------------------------------------------------------
// QKVO GEMM (validated): 128x128 tile, BK=32, 4 waves 2x2.
// m0<768 -> qkT[b][n][m] (q pre-scaled), LDS-staged coalesced epilogue;
// m0>=768 -> vo[b][m-768][n] via swapped-operand MFMA + staged epilogue.
// ---------------------------------------------------------------------------
__global__ __launch_bounds__(256) void gemm_qkvo(
    const unsigned short* __restrict__ Wb16, const unsigned short* __restrict__ Xt,
    const float* __restrict__ bias, unsigned short* __restrict__ qkT,
    unsigned short* __restrict__ vo)
{
    __shared__ __align__(16) unsigned short lds[16896];
    #define AS(r, k) lds[(r) * 40 + (k)]
    #define BS(r, k) lds[5120 + (r) * 40 + (k)]
    #define CS(r, c2) lds[(r) * 132 + (c2)]

    const int b = blockIdx.z, m0 = blockIdx.y * 128, n0 = blockIdx.x * 128;
    const int tid = threadIdx.x;
    const int w = tid >> 6, lane = tid & 63;
    const int wr = w >> 1, wc = w & 1;
    const int g = lane >> 4, c = lane & 15;
    const bool SWAPPED = (m0 >= 768);

    const unsigned short* Xb = Xt + (size_t)b * HWSZ * DIM;

    floatx4 acc[4][4];
    #pragma unroll
    for (int i = 0; i < 4; ++i)
        #pragma unroll
        for (int j = 0; j < 4; ++j) acc[i][j] = (floatx4){0.f, 0.f, 0.f, 0.f};

    const int srow = tid >> 1, shh = (tid & 1) * 16;

    for (int k0 = 0; k0 < DIM; k0 += 32) {
        __syncthreads();
        {
            const unsigned short* wp = &Wb16[(size_t)(m0 + srow) * DIM + k0 + shh];
            *(bf16x8*)&AS(srow, shh)     = *(const bf16x8*)wp;
            *(bf16x8*)&AS(srow, shh + 8) = *(const bf16x8*)(wp + 8);
            const unsigned short* xp = &Xb[(size_t)(n0 + srow) * DIM + k0 + shh];
            *(bf16x8*)&BS(srow, shh)     = *(const bf16x8*)xp;
            *(bf16x8*)&BS(srow, shh + 8) = *(const bf16x8*)(xp + 8);
        }
        __syncthreads();

        bf16x8 af[4], bfj[4];
        #pragma unroll
        for (int i = 0; i < 4; ++i)
            af[i] = *(const bf16x8*)&AS(64 * wr + 16 * i + c, 8 * g);
        #pragma unroll
        for (int j = 0; j < 4; ++j)
            bfj[j] = *(const bf16x8*)&BS(64 * wc + 16 * j + c, 8 * g);
        if (!SWAPPED) {
            #pragma unroll
            for (int i = 0; i < 4; ++i)
                #pragma unroll
                for (int j = 0; j < 4; ++j)
                    acc[i][j] = __builtin_amdgcn_mfma_f32_16x16x32_bf16(
                        af[i], bfj[j], acc[i][j], 0, 0, 0);
        } else {
            #pragma unroll
            for (int i = 0; i < 4; ++i)
                #pragma unroll
                for (int j = 0; j < 4; ++j)
                    acc[i][j] = __builtin_amdgcn_mfma_f32_16x16x32_bf16(
                        bfj[j], af[i], acc[i][j], 0, 0, 0);
        }
    }

    __syncthreads();   // staging readers done; reuse lds as Cs

    if (m0 < 768) {
        const float qs = (m0 < 384) ? EXP_K : 1.0f;
        #pragma unroll
        for (int i = 0; i < 4; ++i) {
            const int mb = 64 * wr + 16 * i + 4 * g;
            float bi[4];
            #pragma unroll
            for (int r = 0; r < 4; ++r) bi[r] = bias[m0 + mb + r];
            #pragma unroll
            for (int j = 0; j < 4; ++j) {
                const int nl = 64 * wc + 16 * j + c;
                ushort4 h;
                h.x = f2bf((acc[i][j][0] + bi[0]) * qs);
                h.y = f2bf((acc[i][j][1] + bi[1]) * qs);
                h.z = f2bf((acc[i][j][2] + bi[2]) * qs);
                h.w = f2bf((acc[i][j][3] + bi[3]) * qs);
                *(ushort4*)&CS(nl, mb) = h;
            }
        }
        __syncthreads();
        const int rl = tid >> 1, half = (tid & 1) * 64;
        unsigned short* dst = &qkT[((size_t)b * HWSZ + n0 + rl) * 768 + m0 + half];
        const unsigned short* src = &CS(rl, half);
        #pragma unroll
        for (int u = 0; u < 8; ++u)
            *(bf16x8*)(dst + 8 * u) = *(const bf16x8*)(src + 8 * u);
    } else {
        #pragma unroll
        for (int i = 0; i < 4; ++i) {
            const int ml = 64 * wr + 16 * i + c;
            const float bi = bias[m0 + ml];
            #pragma unroll
            for (int j = 0; j < 4; ++j) {
                const int nb = 64 * wc + 16 * j + 4 * g;
                ushort4 h;
                h.x = f2bf(acc[i][j][0] + bi);
                h.y = f2bf(acc[i][j][1] + bi);
                h.z = f2bf(acc[i][j][2] + bi);
                h.w = f2bf(acc[i][j][3] + bi);
                *(ushort4*)&CS(ml, nb) = h;
            }
        }
        __syncthreads();
        const int rl = tid >> 1, half = (tid & 1) * 64;
        unsigned short* dst =
            &vo[((size_t)b * 768 + (m0 - 768) + rl) * HWSZ + n0 + half];
        const unsigned short* src = &CS(rl, half);
        #pragma unroll
        for (int u = 0; u < 8; ++u)
            *(bf16x8*)(dst + 8 * u) = *(const bf16x8*)(src + 8 * u);
    }
    #undef AS
    #undef BS
    #undef CS
}

// ---------------------------------------------------------------------------
// Proj GEMM: 64x64 tile, BK=32, 4 waves 2x2 (wave quadrant 32x32 = 2x2 frags).
// Grid (16,6,8)=768 blocks -> 3 blocks/CU.
// ---------------------------------------------------------------------------
__global__ __launch_bounds__(256) void gemm_proj(
    const unsigned short* __restrict__ Wb16, const unsigned short* __restrict__ Xt,
    const float* __restrict__ bias, float* __restrict__ Yf)
{
    __shared__ __align__(16) unsigned short As[64][40];
    __shared__ __align__(16) unsigned short Bs[64][40];

    const int b = blockIdx.z, m0 = blockIdx.y * 64, n0 = blockIdx.x * 64;
    const int tid = threadIdx.x;
    const int w = tid >> 6, lane = tid & 63;
    const int wr = w >> 1, wc = w & 1;
    const int g = lane >> 4, c = lane & 15;

    const unsigned short* Xb = Xt + (size_t)b * HWSZ * DIM;

    floatx4 acc[2][2];
    #pragma unroll
    for (int i = 0; i < 2; ++i)
        #pragma unroll
        for (int j = 0; j < 2; ++j) acc[i][j] = (floatx4){0.f, 0.f, 0.f, 0.f};

    const int srow = tid >> 2, sk8 = (tid & 3) * 8;

    for (int k0 = 0; k0 < DIM; k0 += 32) {
        __syncthreads();
        *(bf16x8*)&As[srow][sk8] =
            *(const bf16x8*)&Wb16[(size_t)(m0 + srow) * DIM + k0 + sk8];
        *(bf16x8*)&Bs[srow][sk8] =
            *(const bf16x8*)&Xb[(size_t)(n0 + srow) * DIM + k0 + sk8];
        __syncthreads();

        bf16x8 af[2], bfj[2];
        #pragma unroll
        for (int i = 0; i < 2; ++i)
            af[i] = *(const bf16x8*)&As[32 * wr + 16 * i + c][8 * g];
        #pragma unroll
        for (int j = 0; j < 2; ++j)
            bfj[j] = *(const bf16x8*)&Bs[32 * wc + 16 * j + c][8 * g];
        #pragma unroll
        for (int i = 0; i < 2; ++i)
            #pragma unroll
            for (int j = 0; j < 2; ++j)
                acc[i][j] = __builtin_amdgcn_mfma_f32_16x16x32_bf16(
                    af[i], bfj[j], acc[i][j], 0, 0, 0);
    }

    #pragma unroll
    for (int i = 0; i < 2; ++i) {
        const int m = m0 + 32 * wr + 16 * i + 4 * g;
        float bi[4];
        #pragma unroll
        for (int r = 0; r < 4; ++r) bi[r] = bias[m + r];
        #pragma unroll
        for (int j = 0; j < 2; ++j) {
            const int n = n0 + 32 * wc + 16 * j + c;
            #pragma unroll
            for (int r = 0; r < 4; ++r)
                Yf[((size_t)b * DIM + m + r) * (size_t)HWSZ + n] = acc[i][j][r] + bi[r];
        }
    }
}

// ---------------------------------------------------------------------------
// MFMA attention, KVBLK=128 (halved barrier count vs round-11) + s_setprio(1)
// around the compute phase (T5). Block = (b, h, 128 p-rows); 8 waves.
// q pre-scaled by EXP_K -> P = exp2(st). Swapped QK^T; P bf16 -> Ps (same-wave).
// Row sums via ones-MFMA (lacc matches oacc row layout; no shuffles).
// ---------------------------------------------------------------------------
__global__ __launch_bounds__(512) void attn_mfma(
    const unsigned short* __restrict__ qkT, const unsigned short* __restrict__ vo,
    unsigned short* __restrict__ res)
{
    __shared__ __align__(16) unsigned short Ks[128][40];   // [j][d]   10.0 KB
    __shared__ __align__(16) unsigned short Vs[32][136];   // [d][j]    8.5 KB
    __shared__ __align__(16) unsigned short Ps[128][136];  // [p][j]   34.0 KB

    const int b = blockIdx.z, h = blockIdx.y, p0 = blockIdx.x * 128;
    const int tid = threadIdx.x;
    const int w = tid >> 6, lane = tid & 63;
    const int g = lane >> 4, c = lane & 15;

    const unsigned short* qkTb = qkT + (size_t)b * HWSZ * 768;
    const unsigned short* vb   = vo + ((size_t)b * 768 + h * HD) * HWSZ;

    // Q B-frag (hoisted): col p = p0+16w+c, k d = 8g+i
    bf16x8 qf = *(const bf16x8*)&qkTb[(size_t)(p0 + 16 * w + c) * 768 + h * HD + 8 * g];

    const bf16x8 onesf = {0x3F80, 0x3F80, 0x3F80, 0x3F80,
                          0x3F80, 0x3F80, 0x3F80, 0x3F80};  // bf16 1.0 x8

    floatx4 oacc0 = (floatx4){0.f, 0.f, 0.f, 0.f};
    floatx4 oacc1 = (floatx4){0.f, 0.f, 0.f, 0.f};
    floatx4 lacc  = (floatx4){0.f, 0.f, 0.f, 0.f};

    for (int j0 = 0; j0 < HWSZ; j0 += 128) {
        __syncthreads();
        if (tid < 256) {
            // K: 128 rows x 32 d; 2 threads/row, 16 ushorts each
            const int jr = tid >> 1, d16 = (tid & 1) * 16;
            const unsigned short* kp =
                &qkTb[(size_t)(j0 + jr) * 768 + 384 + h * HD + d16];
            *(bf16x8*)&Ks[jr][d16]     = *(const bf16x8*)kp;
            *(bf16x8*)&Ks[jr][d16 + 8] = *(const bf16x8*)(kp + 8);
        } else {
            // V: 32 rows x 128 j; 8 threads/row, 16 ushorts each
            const int t = tid - 256;
            const int dr = t >> 3, j16 = (t & 7) * 16;
            const unsigned short* vp = &vb[(size_t)dr * HWSZ + j0 + j16];
            *(bf16x8*)&Vs[dr][j16]     = *(const bf16x8*)vp;
            *(bf16x8*)&Vs[dr][j16 + 8] = *(const bf16x8*)(vp + 8);
        }
        __syncthreads();

        __builtin_amdgcn_s_setprio(1);
        // QK^T (swapped) + exp2 + pack into Ps: 8 jb sub-tiles
        #pragma unroll
        for (int jb = 0; jb < 8; ++jb) {
            bf16x8 kf = *(const bf16x8*)&Ks[jb * 16 + c][8 * g];
            floatx4 st = (floatx4){0.f, 0.f, 0.f, 0.f};
            st = __builtin_amdgcn_mfma_f32_16x16x32_bf16(kf, qf, st, 0, 0, 0);
            ushort4 pe = make_ushort4(f2bf(exp2f(st[0])), f2bf(exp2f(st[1])),
                                      f2bf(exp2f(st[2])), f2bf(exp2f(st[3])));
            *(ushort4*)&Ps[16 * w + c][jb * 16 + 4 * g] = pe;
        }

        // PV + row-sum over 4 jk sub-tiles
        #pragma unroll
        for (int jk = 0; jk < 4; ++jk) {
            bf16x8 pf  = *(const bf16x8*)&Ps[16 * w + c][jk * 32 + 8 * g];
            bf16x8 vf0 = *(const bf16x8*)&Vs[c][jk * 32 + 8 * g];
            bf16x8 vf1 = *(const bf16x8*)&Vs[16 + c][jk * 32 + 8 * g];
            oacc0 = __builtin_amdgcn_mfma_f32_16x16x32_bf16(pf, vf0, oacc0, 0, 0, 0);
            oacc1 = __builtin_amdgcn_mfma_f32_16x16x32_bf16(pf, vf1, oacc1, 0, 0, 0);
            lacc  = __builtin_amdgcn_mfma_f32_16x16x32_bf16(pf, onesf, lacc, 0, 0, 0);
        }
        __builtin_amdgcn_s_setprio(0);
    }

    // lacc[r] = l[p = p0+16w+4g+r] — matches oacc rows.
    float linv[4];
    #pragma unroll
    for (int r = 0; r < 4; ++r) linv[r] = 1.0f / lacc[r];

    unsigned short* rp = res + ((size_t)b * DIM + h * HD) * HWSZ;
    const int pbase = p0 + 16 * w + 4 * g;
    ushort4 h0, h1;
    h0.x = f2bf(oacc0[0] * linv[0]); h0.y = f2bf(oacc0[1] * linv[1]);
    h0.z = f2bf(oacc0[2] * linv[2]); h0.w = f2bf(oacc0[3] * linv[3]);
    h1.x = f2bf(oacc1[0] * linv[0]); h1.y = f2bf(oacc1[1] * linv[1]);
    h1.z = f2bf(oacc1[2] * linv[2]); h1.w = f2bf(oacc1[3] * linv[3]);
    *(ushort4*)&rp[(size_t)c * HWSZ + pbase] = h0;
    *(ushort4*)&rp[(size_t)(16 + c) * HWSZ + pbase] = h1;
}

// ---------------------------------------------------------------------------
// LePE 5x5 depthwise on v + bias, fused gate: gated = (res + lepe(v)) * o.
// ---------------------------------------------------------------------------
__global__ __launch_bounds__(256) void lepe_mul(
    const unsigned short* __restrict__ vo, const float* __restrict__ lw,
    const float* __restrict__ lb, const unsigned short* __restrict__ res,
    unsigned short* __restrict__ gated)
{
    const int cch = blockIdx.x, b = blockIdx.y;
    const unsigned short* v  = vo + ((size_t)b * 768 + cch) * HWSZ;
    const unsigned short* o  = vo + ((size_t)b * 768 + 384 + cch) * HWSZ;
    const unsigned short* rp = res + ((size_t)b * DIM + cch) * HWSZ;
    unsigned short* gp = gated + ((size_t)b * DIM + cch) * HWSZ;

    __shared__ float vs[1024];
    __shared__ float wgt[25];

    const int tid = threadIdx.x;
    {
        ushort4 hv = *(const ushort4*)&v[tid * 4];
        vs[tid * 4 + 0] = bf2f(hv.x); vs[tid * 4 + 1] = bf2f(hv.y);
        vs[tid * 4 + 2] = bf2f(hv.z); vs[tid * 4 + 3] = bf2f(hv.w);
    }
    if (tid < 25) wgt[tid] = lw[cch * 25 + tid];
    __syncthreads();

    const float bias = lb[cch];
    const int q0 = tid * 4;
    const int y  = q0 >> 5;
    const int x0 = q0 & 31;

    float acc[4] = {bias, bias, bias, bias};
    #pragma unroll
    for (int ky = 0; ky < 5; ++ky) {
        int iy = y + ky - 2;
        if ((unsigned)iy < 32u) {
            #pragma unroll
            for (int kx = 0; kx < 5; ++kx) {
                float wv = wgt[ky * 5 + kx];
                #pragma unroll
                for (int u = 0; u < 4; ++u) {
                    int ix = x0 + u + kx - 2;
                    if ((unsigned)ix < 32u) acc[u] += wv * vs[iy * 32 + ix];
                }
            }
        }
    }

    ushort4 rh = *(const ushort4*)&rp[q0];
    ushort4 oh = *(const ushort4*)&o[q0];
    ushort4 outv;
    outv.x = f2bf((bf2f(rh.x) + acc[0]) * bf2f(oh.x));
    outv.y = f2bf((bf2f(rh.y) + acc[1]) * bf2f(oh.y));
    outv.z = f2bf((bf2f(rh.z) + acc[2]) * bf2f(oh.z));
    outv.w = f2bf((bf2f(rh.w) + acc[3]) * bf2f(oh.w));
    *(ushort4*)&gp[q0] = outv;
}

// ---------------------------------------------------------------------------
extern "C" void kernel_launch(void* const* d_in, const int* in_sizes, int n_in,
                              void* d_out, int out_size, void* d_ws, size_t ws_size,
                              hipStream_t stream)
{
    const float* x      = (const float*)d_in[0];
    const float* qkvo_w = (const float*)d_in[1];
    const float* qkvo_b = (const float*)d_in[2];
    const float* lepe_w = (const float*)d_in[3];
    const float* lepe_b = (const float*)d_in[4];
    const float* proj_w = (const float*)d_in[5];
    const float* proj_b = (const float*)d_in[6];

    unsigned short* xt     = (unsigned short*)d_ws;                    // 8*1024*384
    unsigned short* qkT    = xt     + (size_t)BATCH * HWSZ * DIM;      // 8*1024*768
    unsigned short* vo     = qkT    + (size_t)BATCH * HWSZ * 768;      // 8*768*1024
    unsigned short* res    = vo     + (size_t)BATCH * 768 * HWSZ;      // 8*384*1024
    unsigned short* gated  = res    + (size_t)BATCH * DIM * HWSZ;      // 8*384*1024
    unsigned short* gatedT = gated  + (size_t)BATCH * DIM * HWSZ;      // 8*1024*384
    unsigned short* wqb    = gatedT + (size_t)BATCH * HWSZ * DIM;      // 1536*384
    unsigned short* wpb    = wqb    + (size_t)1536 * DIM;              // 384*384

    // 1. prep: x -> xt (transpose+cast) AND weights -> bf16
    prep<<<dim3(32, 12, 9), 256, 0, stream>>>(x, qkvo_w, proj_w, xt, wqb, wpb);

    // 2. QKVO projection -> qkT (q,k transposed; q pre-scaled) + vo
    gemm_qkvo<<<dim3(8, 12, BATCH), 256, 0, stream>>>(wqb, xt, qkvo_b, qkT, vo);

    // 3. Attention -> res [b][384][1024] bf16
    attn_mfma<<<dim3(8, NH, BATCH), 512, 0, stream>>>(qkT, vo, res);

    // 4. gated = (res + lepe(v)) * o
    lepe_mul<<<dim3(DIM, BATCH), 256, 0, stream>>>(vo, lepe_w, lepe_b, res, gated);

    // 5. gated -> gatedT [b][1024][384] bf16
    tcast_b16<<<dim3(32, 12, BATCH), 256, 0, stream>>>(gated, gatedT, DIM, HWSZ);

    // 6. proj GEMM -> out f32 (64x64 tiles, 768 blocks)
    gemm_proj<<<dim3(16, 6, BATCH), 256, 0, stream>>>(wpb, gatedT, proj_b, (float*)d_out);
}

// Round 13
// 166.219 us; speedup vs baseline: 1.3028x; 1.0189x over previous
//
#include <hip/hip_runtime.h>
#include <hip/hip_bf16.h>

#define DIM   384
#define NH    12
#define HD    32
#define HWSZ  1024
#define BATCH 8
#define SCALE 0.17677669529663687f          // 32^-0.5
#define EXP_K (SCALE * 1.4426950408889634f) // SCALE * log2(e): q pre-scale for exp2

typedef __attribute__((ext_vector_type(8))) short bf16x8;
typedef __attribute__((ext_vector_type(4))) float floatx4;

__device__ __forceinline__ unsigned short f2bf(float x) {
    union { __hip_bfloat16 h; unsigned short u; } c;
    c.h = __float2bfloat16(x);          // native v_cvt (RNE)
    return c.u;
}
__device__ __forceinline__ float bf2f(unsigned short h) {
    union { unsigned int u; float f; } v; v.u = ((unsigned int)h) << 16;
    return v.f;
}

// ---------------------------------------------------------------------------
// Prep: z<8 -> transpose+cast x [B][384][1024] f32 -> xt [B][1024][384] bf16;
//       z==8 -> cast qkvo_w/proj_w f32 -> bf16 (linearized over x,y).
// ---------------------------------------------------------------------------
__global__ __launch_bounds__(256) void prep(
    const float* __restrict__ x, const float* __restrict__ qkvo_w,
    const float* __restrict__ proj_w, unsigned short* __restrict__ xt,
    unsigned short* __restrict__ wqb, unsigned short* __restrict__ wpb)
{
    const int tid = threadIdx.x;
    if (blockIdx.z < 8) {
        __shared__ __align__(16) unsigned short t[32][36];
        const int n0 = blockIdx.x * 32, c0 = blockIdx.y * 32, b = blockIdx.z;
        const float* ib = x + (size_t)b * DIM * HWSZ;
        unsigned short* ob = xt + (size_t)b * HWSZ * DIM;
        const int r = tid >> 3, q = (tid & 7) * 4;
        float4 f = *(const float4*)&ib[(size_t)(c0 + r) * HWSZ + n0 + q];
        ushort4 h = make_ushort4(f2bf(f.x), f2bf(f.y), f2bf(f.z), f2bf(f.w));
        *(ushort4*)&t[r][q] = h;
        __syncthreads();
        ushort4 o;
        o.x = t[q + 0][r]; o.y = t[q + 1][r]; o.z = t[q + 2][r]; o.w = t[q + 3][r];
        *(ushort4*)&ob[(size_t)(n0 + r) * DIM + c0 + q] = o;
    } else {
        const int idx = (blockIdx.y * 32 + blockIdx.x) * 256 + tid;
        if (idx >= 92160) return;          // 73728 + 18432
        const float* src; unsigned short* dst; int i;
        if (idx < 73728) { src = qkvo_w; dst = wqb; i = idx; }
        else             { src = proj_w; dst = wpb; i = idx - 73728; }
        float4 f0 = *(const float4*)&src[i * 8];
        float4 f1 = *(const float4*)&src[i * 8 + 4];
        ushort4 h0 = make_ushort4(f2bf(f0.x), f2bf(f0.y), f2bf(f0.z), f2bf(f0.w));
        ushort4 h1 = make_ushort4(f2bf(f1.x), f2bf(f1.y), f2bf(f1.z), f2bf(f1.w));
        *(ushort4*)&dst[i * 8] = h0;
        *(ushort4*)&dst[i * 8 + 4] = h1;
    }
}

// ---------------------------------------------------------------------------
// Transpose bf16: in [B][C][N] -> out [B][N][C].  grid(N/32, C/32, B)
// ---------------------------------------------------------------------------
__global__ __launch_bounds__(256) void tcast_b16(
    const unsigned short* __restrict__ in, unsigned short* __restrict__ out, int C, int N)
{
    __shared__ __align__(16) unsigned short t[32][36];
    const int n0 = blockIdx.x * 32, c0 = blockIdx.y * 32, b = blockIdx.z;
    const unsigned short* ib = in + (size_t)b * C * N;
    unsigned short* ob = out + (size_t)b * N * C;
    const int tid = threadIdx.x;
    const int r = tid >> 3, q = (tid & 7) * 4;
    ushort4 h = *(const ushort4*)&ib[(size_t)(c0 + r) * N + n0 + q];
    *(ushort4*)&t[r][q] = h;
    __syncthreads();
    ushort4 o;
    o.x = t[q + 0][r]; o.y = t[q + 1][r]; o.z = t[q + 2][r]; o.w = t[q + 3][r];
    *(ushort4*)&ob[(size_t)(n0 + r) * C + c0 + q] = o;
}

// ---------------------------------------------------------------------------
// QKVO GEMM: 128x128 tile, BK=64 (3 k-steps, 6 barriers), 4 waves 2x2.
// Per k-step: 2 half-K sub-phases x 16 MFMA. K-slice order identical to BK=32
// version -> bitwise-identical accumulation.
// m0<768 -> qkT[b][n][m] (q pre-scaled), LDS-staged coalesced epilogue;
// m0>=768 -> vo[b][m-768][n] via swapped-operand MFMA + staged epilogue.
// ---------------------------------------------------------------------------
__global__ __launch_bounds__(256) void gemm_qkvo(
    const unsigned short* __restrict__ Wb16, const unsigned short* __restrict__ Xt,
    const float* __restrict__ bias, unsigned short* __restrict__ qkT,
    unsigned short* __restrict__ vo)
{
    // Staging As[128][72]+Bs[128][72] = 36.9KB; epilogue Cs[128][132] = 33.8KB.
    __shared__ __align__(16) unsigned short lds[18432];
    #define AS(r, k) lds[(r) * 72 + (k)]
    #define BS(r, k) lds[9216 + (r) * 72 + (k)]
    #define CS(r, c2) lds[(r) * 132 + (c2)]

    const int b = blockIdx.z, m0 = blockIdx.y * 128, n0 = blockIdx.x * 128;
    const int tid = threadIdx.x;
    const int w = tid >> 6, lane = tid & 63;
    const int wr = w >> 1, wc = w & 1;
    const int g = lane >> 4, c = lane & 15;
    const bool SWAPPED = (m0 >= 768);

    const unsigned short* Xb = Xt + (size_t)b * HWSZ * DIM;

    floatx4 acc[4][4];
    #pragma unroll
    for (int i = 0; i < 4; ++i)
        #pragma unroll
        for (int j = 0; j < 4; ++j) acc[i][j] = (floatx4){0.f, 0.f, 0.f, 0.f};

    const int srow = tid >> 1, sh = (tid & 1) * 32;   // 2 thr/row, 32 ushorts each

    for (int k0 = 0; k0 < DIM; k0 += 64) {
        __syncthreads();
        {
            const unsigned short* wp = &Wb16[(size_t)(m0 + srow) * DIM + k0 + sh];
            *(bf16x8*)&AS(srow, sh)      = *(const bf16x8*)wp;
            *(bf16x8*)&AS(srow, sh + 8)  = *(const bf16x8*)(wp + 8);
            *(bf16x8*)&AS(srow, sh + 16) = *(const bf16x8*)(wp + 16);
            *(bf16x8*)&AS(srow, sh + 24) = *(const bf16x8*)(wp + 24);
            const unsigned short* xp = &Xb[(size_t)(n0 + srow) * DIM + k0 + sh];
            *(bf16x8*)&BS(srow, sh)      = *(const bf16x8*)xp;
            *(bf16x8*)&BS(srow, sh + 8)  = *(const bf16x8*)(xp + 8);
            *(bf16x8*)&BS(srow, sh + 16) = *(const bf16x8*)(xp + 16);
            *(bf16x8*)&BS(srow, sh + 24) = *(const bf16x8*)(xp + 24);
        }
        __syncthreads();

        #pragma unroll
        for (int half = 0; half < 2; ++half) {
            const int kc = 32 * half + 8 * g;
            bf16x8 af[4], bfj[4];
            #pragma unroll
            for (int i = 0; i < 4; ++i)
                af[i] = *(const bf16x8*)&AS(64 * wr + 16 * i + c, kc);
            #pragma unroll
            for (int j = 0; j < 4; ++j)
                bfj[j] = *(const bf16x8*)&BS(64 * wc + 16 * j + c, kc);
            if (!SWAPPED) {
                #pragma unroll
                for (int i = 0; i < 4; ++i)
                    #pragma unroll
                    for (int j = 0; j < 4; ++j)
                        acc[i][j] = __builtin_amdgcn_mfma_f32_16x16x32_bf16(
                            af[i], bfj[j], acc[i][j], 0, 0, 0);
            } else {
                #pragma unroll
                for (int i = 0; i < 4; ++i)
                    #pragma unroll
                    for (int j = 0; j < 4; ++j)
                        acc[i][j] = __builtin_amdgcn_mfma_f32_16x16x32_bf16(
                            bfj[j], af[i], acc[i][j], 0, 0, 0);
            }
        }
    }

    __syncthreads();   // staging readers done; reuse lds as Cs

    if (m0 < 768) {
        const float qs = (m0 < 384) ? EXP_K : 1.0f;
        #pragma unroll
        for (int i = 0; i < 4; ++i) {
            const int mb = 64 * wr + 16 * i + 4 * g;
            float bi[4];
            #pragma unroll
            for (int r = 0; r < 4; ++r) bi[r] = bias[m0 + mb + r];
            #pragma unroll
            for (int j = 0; j < 4; ++j) {
                const int nl = 64 * wc + 16 * j + c;
                ushort4 h;
                h.x = f2bf((acc[i][j][0] + bi[0]) * qs);
                h.y = f2bf((acc[i][j][1] + bi[1]) * qs);
                h.z = f2bf((acc[i][j][2] + bi[2]) * qs);
                h.w = f2bf((acc[i][j][3] + bi[3]) * qs);
                *(ushort4*)&CS(nl, mb) = h;
            }
        }
        __syncthreads();
        const int rl = tid >> 1, half = (tid & 1) * 64;
        unsigned short* dst = &qkT[((size_t)b * HWSZ + n0 + rl) * 768 + m0 + half];
        const unsigned short* src = &CS(rl, half);
        #pragma unroll
        for (int u = 0; u < 8; ++u)
            *(bf16x8*)(dst + 8 * u) = *(const bf16x8*)(src + 8 * u);
    } else {
        #pragma unroll
        for (int i = 0; i < 4; ++i) {
            const int ml = 64 * wr + 16 * i + c;
            const float bi = bias[m0 + ml];
            #pragma unroll
            for (int j = 0; j < 4; ++j) {
                const int nb = 64 * wc + 16 * j + 4 * g;
                ushort4 h;
                h.x = f2bf(acc[i][j][0] + bi);
                h.y = f2bf(acc[i][j][1] + bi);
                h.z = f2bf(acc[i][j][2] + bi);
                h.w = f2bf(acc[i][j][3] + bi);
                *(ushort4*)&CS(ml, nb) = h;
            }
        }
        __syncthreads();
        const int rl = tid >> 1, half = (tid & 1) * 64;
        unsigned short* dst =
            &vo[((size_t)b * 768 + (m0 - 768) + rl) * HWSZ + n0 + half];
        const unsigned short* src = &CS(rl, half);
        #pragma unroll
        for (int u = 0; u < 8; ++u)
            *(bf16x8*)(dst + 8 * u) = *(const bf16x8*)(src + 8 * u);
    }
    #undef AS
    #undef BS
    #undef CS
}

// ---------------------------------------------------------------------------
// Proj GEMM: 64x64 tile, BK=64 (6 k-steps), 4 waves 2x2 (2x2 frags each).
// Grid (16,6,8)=768 blocks -> 3 blocks/CU.
// ---------------------------------------------------------------------------
__global__ __launch_bounds__(256) void gemm_proj(
    const unsigned short* __restrict__ Wb16, const unsigned short* __restrict__ Xt,
    const float* __restrict__ bias, float* __restrict__ Yf)
{
    __shared__ __align__(16) unsigned short As[64][72];
    __shared__ __align__(16) unsigned short Bs[64][72];

    const int b = blockIdx.z, m0 = blockIdx.y * 64, n0 = blockIdx.x * 64;
    const int tid = threadIdx.x;
    const int w = tid >> 6, lane = tid & 63;
    const int wr = w >> 1, wc = w & 1;
    const int g = lane >> 4, c = lane & 15;

    const unsigned short* Xb = Xt + (size_t)b * HWSZ * DIM;

    floatx4 acc[2][2];
    #pragma unroll
    for (int i = 0; i < 2; ++i)
        #pragma unroll
        for (int j = 0; j < 2; ++j) acc[i][j] = (floatx4){0.f, 0.f, 0.f, 0.f};

    const int srow = tid >> 2, sh = (tid & 3) * 16;   // 4 thr/row, 16 ushorts each

    for (int k0 = 0; k0 < DIM; k0 += 64) {
        __syncthreads();
        {
            const unsigned short* wp = &Wb16[(size_t)(m0 + srow) * DIM + k0 + sh];
            *(bf16x8*)&As[srow][sh]     = *(const bf16x8*)wp;
            *(bf16x8*)&As[srow][sh + 8] = *(const bf16x8*)(wp + 8);
            const unsigned short* xp = &Xb[(size_t)(n0 + srow) * DIM + k0 + sh];
            *(bf16x8*)&Bs[srow][sh]     = *(const bf16x8*)xp;
            *(bf16x8*)&Bs[srow][sh + 8] = *(const bf16x8*)(xp + 8);
        }
        __syncthreads();

        #pragma unroll
        for (int half = 0; half < 2; ++half) {
            const int kc = 32 * half + 8 * g;
            bf16x8 af[2], bfj[2];
            #pragma unroll
            for (int i = 0; i < 2; ++i)
                af[i] = *(const bf16x8*)&As[32 * wr + 16 * i + c][kc];
            #pragma unroll
            for (int j = 0; j < 2; ++j)
                bfj[j] = *(const bf16x8*)&Bs[32 * wc + 16 * j + c][kc];
            #pragma unroll
            for (int i = 0; i < 2; ++i)
                #pragma unroll
                for (int j = 0; j < 2; ++j)
                    acc[i][j] = __builtin_amdgcn_mfma_f32_16x16x32_bf16(
                        af[i], bfj[j], acc[i][j], 0, 0, 0);
        }
    }

    #pragma unroll
    for (int i = 0; i < 2; ++i) {
        const int m = m0 + 32 * wr + 16 * i + 4 * g;
        float bi[4];
        #pragma unroll
        for (int r = 0; r < 4; ++r) bi[r] = bias[m + r];
        #pragma unroll
        for (int j = 0; j < 2; ++j) {
            const int n = n0 + 32 * wc + 16 * j + c;
            #pragma unroll
            for (int r = 0; r < 4; ++r)
                Yf[((size_t)b * DIM + m + r) * (size_t)HWSZ + n] = acc[i][j][r] + bi[r];
        }
    }
}

// ---------------------------------------------------------------------------
// MFMA attention (validated round-12): KVBLK=128, s_setprio around compute.
// Block = (b, h, 128 p-rows); 8 waves. q pre-scaled -> P = exp2(st).
// Swapped QK^T; P bf16 -> Ps (same-wave). Row sums via ones-MFMA.
// ---------------------------------------------------------------------------
__global__ __launch_bounds__(512) void attn_mfma(
    const unsigned short* __restrict__ qkT, const unsigned short* __restrict__ vo,
    unsigned short* __restrict__ res)
{
    __shared__ __align__(16) unsigned short Ks[128][40];   // [j][d]   10.0 KB
    __shared__ __align__(16) unsigned short Vs[32][136];   // [d][j]    8.5 KB
    __shared__ __align__(16) unsigned short Ps[128][136];  // [p][j]   34.0 KB

    const int b = blockIdx.z, h = blockIdx.y, p0 = blockIdx.x * 128;
    const int tid = threadIdx.x;
    const int w = tid >> 6, lane = tid & 63;
    const int g = lane >> 4, c = lane & 15;

    const unsigned short* qkTb = qkT + (size_t)b * HWSZ * 768;
    const unsigned short* vb   = vo + ((size_t)b * 768 + h * HD) * HWSZ;

    bf16x8 qf = *(const bf16x8*)&qkTb[(size_t)(p0 + 16 * w + c) * 768 + h * HD + 8 * g];

    const bf16x8 onesf = {0x3F80, 0x3F80, 0x3F80, 0x3F80,
                          0x3F80, 0x3F80, 0x3F80, 0x3F80};  // bf16 1.0 x8

    floatx4 oacc0 = (floatx4){0.f, 0.f, 0.f, 0.f};
    floatx4 oacc1 = (floatx4){0.f, 0.f, 0.f, 0.f};
    floatx4 lacc  = (floatx4){0.f, 0.f, 0.f, 0.f};

    for (int j0 = 0; j0 < HWSZ; j0 += 128) {
        __syncthreads();
        if (tid < 256) {
            const int jr = tid >> 1, d16 = (tid & 1) * 16;
            const unsigned short* kp =
                &qkTb[(size_t)(j0 + jr) * 768 + 384 + h * HD + d16];
            *(bf16x8*)&Ks[jr][d16]     = *(const bf16x8*)kp;
            *(bf16x8*)&Ks[jr][d16 + 8] = *(const bf16x8*)(kp + 8);
        } else {
            const int t = tid - 256;
            const int dr = t >> 3, j16 = (t & 7) * 16;
            const unsigned short* vp = &vb[(size_t)dr * HWSZ + j0 + j16];
            *(bf16x8*)&Vs[dr][j16]     = *(const bf16x8*)vp;
            *(bf16x8*)&Vs[dr][j16 + 8] = *(const bf16x8*)(vp + 8);
        }
        __syncthreads();

        __builtin_amdgcn_s_setprio(1);
        #pragma unroll
        for (int jb = 0; jb < 8; ++jb) {
            bf16x8 kf = *(const bf16x8*)&Ks[jb * 16 + c][8 * g];
            floatx4 st = (floatx4){0.f, 0.f, 0.f, 0.f};
            st = __builtin_amdgcn_mfma_f32_16x16x32_bf16(kf, qf, st, 0, 0, 0);
            ushort4 pe = make_ushort4(f2bf(exp2f(st[0])), f2bf(exp2f(st[1])),
                                      f2bf(exp2f(st[2])), f2bf(exp2f(st[3])));
            *(ushort4*)&Ps[16 * w + c][jb * 16 + 4 * g] = pe;
        }

        #pragma unroll
        for (int jk = 0; jk < 4; ++jk) {
            bf16x8 pf  = *(const bf16x8*)&Ps[16 * w + c][jk * 32 + 8 * g];
            bf16x8 vf0 = *(const bf16x8*)&Vs[c][jk * 32 + 8 * g];
            bf16x8 vf1 = *(const bf16x8*)&Vs[16 + c][jk * 32 + 8 * g];
            oacc0 = __builtin_amdgcn_mfma_f32_16x16x32_bf16(pf, vf0, oacc0, 0, 0, 0);
            oacc1 = __builtin_amdgcn_mfma_f32_16x16x32_bf16(pf, vf1, oacc1, 0, 0, 0);
            lacc  = __builtin_amdgcn_mfma_f32_16x16x32_bf16(pf, onesf, lacc, 0, 0, 0);
        }
        __builtin_amdgcn_s_setprio(0);
    }

    float linv[4];
    #pragma unroll
    for (int r = 0; r < 4; ++r) linv[r] = 1.0f / lacc[r];

    unsigned short* rp = res + ((size_t)b * DIM + h * HD) * HWSZ;
    const int pbase = p0 + 16 * w + 4 * g;
    ushort4 h0, h1;
    h0.x = f2bf(oacc0[0] * linv[0]); h0.y = f2bf(oacc0[1] * linv[1]);
    h0.z = f2bf(oacc0[2] * linv[2]); h0.w = f2bf(oacc0[3] * linv[3]);
    h1.x = f2bf(oacc1[0] * linv[0]); h1.y = f2bf(oacc1[1] * linv[1]);
    h1.z = f2bf(oacc1[2] * linv[2]); h1.w = f2bf(oacc1[3] * linv[3]);
    *(ushort4*)&rp[(size_t)c * HWSZ + pbase] = h0;
    *(ushort4*)&rp[(size_t)(16 + c) * HWSZ + pbase] = h1;
}

// ---------------------------------------------------------------------------
// LePE 5x5 depthwise on v + bias, fused gate: gated = (res + lepe(v)) * o.
// ---------------------------------------------------------------------------
__global__ __launch_bounds__(256) void lepe_mul(
    const unsigned short* __restrict__ vo, const float* __restrict__ lw,
    const float* __restrict__ lb, const unsigned short* __restrict__ res,
    unsigned short* __restrict__ gated)
{
    const int cch = blockIdx.x, b = blockIdx.y;
    const unsigned short* v  = vo + ((size_t)b * 768 + cch) * HWSZ;
    const unsigned short* o  = vo + ((size_t)b * 768 + 384 + cch) * HWSZ;
    const unsigned short* rp = res + ((size_t)b * DIM + cch) * HWSZ;
    unsigned short* gp = gated + ((size_t)b * DIM + cch) * HWSZ;

    __shared__ float vs[1024];
    __shared__ float wgt[25];

    const int tid = threadIdx.x;
    {
        ushort4 hv = *(const ushort4*)&v[tid * 4];
        vs[tid * 4 + 0] = bf2f(hv.x); vs[tid * 4 + 1] = bf2f(hv.y);
        vs[tid * 4 + 2] = bf2f(hv.z); vs[tid * 4 + 3] = bf2f(hv.w);
    }
    if (tid < 25) wgt[tid] = lw[cch * 25 + tid];
    __syncthreads();

    const float bias = lb[cch];
    const int q0 = tid * 4;
    const int y  = q0 >> 5;
    const int x0 = q0 & 31;

    float acc[4] = {bias, bias, bias, bias};
    #pragma unroll
    for (int ky = 0; ky < 5; ++ky) {
        int iy = y + ky - 2;
        if ((unsigned)iy < 32u) {
            #pragma unroll
            for (int kx = 0; kx < 5; ++kx) {
                float wv = wgt[ky * 5 + kx];
                #pragma unroll
                for (int u = 0; u < 4; ++u) {
                    int ix = x0 + u + kx - 2;
                    if ((unsigned)ix < 32u) acc[u] += wv * vs[iy * 32 + ix];
                }
            }
        }
    }

    ushort4 rh = *(const ushort4*)&rp[q0];
    ushort4 oh = *(const ushort4*)&o[q0];
    ushort4 outv;
    outv.x = f2bf((bf2f(rh.x) + acc[0]) * bf2f(oh.x));
    outv.y = f2bf((bf2f(rh.y) + acc[1]) * bf2f(oh.y));
    outv.z = f2bf((bf2f(rh.z) + acc[2]) * bf2f(oh.z));
    outv.w = f2bf((bf2f(rh.w) + acc[3]) * bf2f(oh.w));
    *(ushort4*)&gp[q0] = outv;
}

// ---------------------------------------------------------------------------
extern "C" void kernel_launch(void* const* d_in, const int* in_sizes, int n_in,
                              void* d_out, int out_size, void* d_ws, size_t ws_size,
                              hipStream_t stream)
{
    const float* x      = (const float*)d_in[0];
    const float* qkvo_w = (const float*)d_in[1];
    const float* qkvo_b = (const float*)d_in[2];
    const float* lepe_w = (const float*)d_in[3];
    const float* lepe_b = (const float*)d_in[4];
    const float* proj_w = (const float*)d_in[5];
    const float* proj_b = (const float*)d_in[6];

    unsigned short* xt     = (unsigned short*)d_ws;                    // 8*1024*384
    unsigned short* qkT    = xt     + (size_t)BATCH * HWSZ * DIM;      // 8*1024*768
    unsigned short* vo     = qkT    + (size_t)BATCH * HWSZ * 768;      // 8*768*1024
    unsigned short* res    = vo     + (size_t)BATCH * 768 * HWSZ;      // 8*384*1024
    unsigned short* gated  = res    + (size_t)BATCH * DIM * HWSZ;      // 8*384*1024
    unsigned short* gatedT = gated  + (size_t)BATCH * DIM * HWSZ;      // 8*1024*384
    unsigned short* wqb    = gatedT + (size_t)BATCH * HWSZ * DIM;      // 1536*384
    unsigned short* wpb    = wqb    + (size_t)1536 * DIM;              // 384*384

    // 1. prep: x -> xt (transpose+cast) AND weights -> bf16
    prep<<<dim3(32, 12, 9), 256, 0, stream>>>(x, qkvo_w, proj_w, xt, wqb, wpb);

    // 2. QKVO projection -> qkT (q,k transposed; q pre-scaled) + vo
    gemm_qkvo<<<dim3(8, 12, BATCH), 256, 0, stream>>>(wqb, xt, qkvo_b, qkT, vo);

    // 3. Attention -> res [b][384][1024] bf16
    attn_mfma<<<dim3(8, NH, BATCH), 512, 0, stream>>>(qkT, vo, res);

    // 4. gated = (res + lepe(v)) * o
    lepe_mul<<<dim3(DIM, BATCH), 256, 0, stream>>>(vo, lepe_w, lepe_b, res, gated);

    // 5. gated -> gatedT [b][1024][384] bf16
    tcast_b16<<<dim3(32, 12, BATCH), 256, 0, stream>>>(gated, gatedT, DIM, HWSZ);

    // 6. proj GEMM -> out f32 (64x64 tiles, BK=64, 768 blocks)
    gemm_proj<<<dim3(16, 6, BATCH), 256, 0, stream>>>(wpb, gatedT, proj_b, (float*)d_out);
}